// Round 10
// baseline (285.659 us; speedup 1.0000x reference)
//
#include <hip/hip_runtime.h>

#define NLVL 14
#define NSHARD 16

struct ZeroArgs { unsigned long long zoff[13]; };

struct TailArgs {
    char* ws;
    const float* wm1; const float* bm1;
    const float* wm2; const float* bm2;
    float* out;
    unsigned long long idx7, idx8, idx9, idx10;
    unsigned long long nbr7, nbr8, nbr9, nbr10;
    unsigned long long val6, val7, val8, val9;
    int cap7, cap8, cap9, cap10;
};

__device__ __forceinline__ float fma4(float4 v, float4 w, float acc) {
    acc = fmaf(v.x, w.x, acc);
    acc = fmaf(v.y, w.y, acc);
    acc = fmaf(v.z, w.z, acc);
    return fmaf(v.w, w.w, acc);
}

__device__ __forceinline__ int cnt_load(const int* p) {
    // agent-scope atomic load: bypasses the CU L1 so we never see a line that
    // was cached before a same-kernel atomicAdd updated it at L2.
    return __hip_atomic_load(p, __ATOMIC_RELAXED, __HIP_MEMORY_SCOPE_AGENT);
}

// async global->LDS, 16 B per lane, wave-uniform LDS base + lane*16 dest.
#define GLDS16(gsrc, ldst) __builtin_amdgcn_global_load_lds( \
    (const __attribute__((address_space(1))) void*)(gsrc),   \
    (__attribute__((address_space(3))) void*)(ldst), 16, 0, 0)

// exclusive prefix over a 256-thread block, one atomicAdd per block.
// Entry __syncthreads makes it loop/multi-call reentrant (protects wsum reuse).
__device__ __forceinline__ int block_scan_base(int mycnt, int* gcnt, int& myoff) {
    __shared__ int wsum[4];
    __shared__ int base;
    __syncthreads();
    int lane = threadIdx.x & 63, wid = threadIdx.x >> 6;
    int scan = mycnt;
    #pragma unroll
    for (int d = 1; d < 64; d <<= 1) {
        int tv = __shfl_up(scan, d, 64);
        if (lane >= d) scan += tv;
    }
    if (lane == 63) wsum[wid] = scan;
    __syncthreads();
    if (threadIdx.x == 0) {
        int tot = 0;
        #pragma unroll
        for (int i = 0; i < 4; i++) { int tv = wsum[i]; wsum[i] = tot; tot += tv; }
        base = tot ? atomicAdd(gcnt, tot) : 0;
    }
    __syncthreads();
    myoff = wsum[wid] + scan - mycnt;
    return base;
}

// ---- level-0 mask compaction tile ----
__device__ void compact0_tile(const float4* __restrict__ mask4, int* __restrict__ idxmap,
                              int* __restrict__ coords, int* __restrict__ cnt, int cap, int tile) {
    int t = threadIdx.x;
    int g0 = tile * 1024 + t;
    float4 m[4];
    #pragma unroll
    for (int j = 0; j < 4; j++) m[j] = mask4[g0 + j * 256];
    int pr[16];
    int mycnt = 0;
    #pragma unroll
    for (int j = 0; j < 4; j++) {
        pr[4 * j + 0] = m[j].x > 0.5f;
        pr[4 * j + 1] = m[j].y > 0.5f;
        pr[4 * j + 2] = m[j].z > 0.5f;
        pr[4 * j + 3] = m[j].w > 0.5f;
        mycnt += pr[4 * j] + pr[4 * j + 1] + pr[4 * j + 2] + pr[4 * j + 3];
    }
    int myoff;
    int base = block_scan_base(mycnt, cnt, myoff);
    int slot = base + myoff;
    #pragma unroll
    for (int j = 0; j < 4; j++) {
        int e0 = (g0 + j * 256) << 2;
        int wv[4];
        #pragma unroll
        for (int k = 0; k < 4; k++) {
            wv[k] = -1;
            if (pr[4 * j + k]) {
                int sl = slot++;
                if (sl < cap) { wv[k] = sl; coords[sl] = e0 + k; }
            }
        }
        *(int4*)(idxmap + e0) = make_int4(wv[0], wv[1], wv[2], wv[3]);
    }
}

// ---- downsample + neighbor lists (byte offsets into vals_{l-1}, zero-row remap) ----
__device__ void down_nbr(const int* __restrict__ idx_in, int HinB,
                         int* __restrict__ idx_out, int* __restrict__ nbr_out,
                         int* __restrict__ cnt_out, int HoutB, int cap_out,
                         int zofs, int bb) {
    int Hout = 1 << HoutB, Hin = 1 << HinB;
    int S = Hout * Hout;
    int S4 = (S + 3) >> 2;
    int o4 = bb * 256 + threadIdx.x;
    int e0 = o4 << 2;
    int jv[4][9];
    int pr[4] = {0, 0, 0, 0};
    #pragma unroll
    for (int k = 0; k < 4; k++)
        #pragma unroll
        for (int tap = 0; tap < 9; tap++) jv[k][tap] = -1;
    if (o4 < S4) {
        if (HoutB >= 2) {
            int r = e0 >> HoutB, c0 = e0 & (Hout - 1);
            int w[3][12];
            #pragma unroll
            for (int a = 0; a < 3; a++) {
                int rr = 2 * r + a - 1;
                bool rok = (unsigned)rr < (unsigned)Hin;
                const int* rowp = idx_in + ((size_t)(rok ? rr : 0) << HinB) + 2 * c0;
                int4 L = (rok && c0 > 0) ? *(const int4*)(rowp - 4) : make_int4(-1, -1, -1, -1);
                int4 M = rok ? *(const int4*)rowp : make_int4(-1, -1, -1, -1);
                int4 R = rok ? *(const int4*)(rowp + 4) : make_int4(-1, -1, -1, -1);
                w[a][0] = L.x; w[a][1] = L.y; w[a][2]  = L.z; w[a][3]  = L.w;
                w[a][4] = M.x; w[a][5] = M.y; w[a][6]  = M.z; w[a][7]  = M.w;
                w[a][8] = R.x; w[a][9] = R.y; w[a][10] = R.z; w[a][11] = R.w;
            }
            #pragma unroll
            for (int k = 0; k < 4; k++) {
                #pragma unroll
                for (int a = 0; a < 3; a++)
                    #pragma unroll
                    for (int b = 0; b < 3; b++)
                        jv[k][a * 3 + b] = w[a][2 * k + b + 3];
                pr[k] = ((jv[k][4] & jv[k][5] & jv[k][7] & jv[k][8]) >= 0);
            }
        } else {   // Hout 1 or 2 (scalar path)
            #pragma unroll
            for (int k = 0; k < 4; k++) {
                int p = e0 + k;
                if (p < S) {
                    int r = p >> HoutB, c = p & (Hout - 1);
                    #pragma unroll
                    for (int a = 0; a < 3; a++)
                        #pragma unroll
                        for (int b = 0; b < 3; b++) {
                            int rr = 2 * r + a - 1, cc = 2 * c + b - 1;
                            if ((unsigned)rr < (unsigned)Hin && (unsigned)cc < (unsigned)Hin)
                                jv[k][a * 3 + b] = idx_in[((size_t)rr << HinB) + cc];
                        }
                    pr[k] = ((jv[k][4] & jv[k][5] & jv[k][7] & jv[k][8]) >= 0);
                }
            }
        }
    }
    int mycnt = pr[0] + pr[1] + pr[2] + pr[3];
    int myoff;
    int base = block_scan_base(mycnt, cnt_out, myoff);
    int slot = base + myoff;
    int wv[4] = {-1, -1, -1, -1};
    #pragma unroll
    for (int k = 0; k < 4; k++) {
        if (pr[k]) {
            int sl = slot++;
            if (sl < cap_out) {
                wv[k] = sl;
                #pragma unroll
                for (int tap = 0; tap < 9; tap++) {
                    int j = jv[k][tap];
                    nbr_out[sl * 9 + tap] = (j < 0) ? zofs : (j << 7);
                }
            }
        }
    }
    if (o4 < S4) {
        if (S >= 4) *(int4*)(idx_out + e0) = make_int4(wv[0], wv[1], wv[2], wv[3]);
        else {
            #pragma unroll
            for (int k = 0; k < 4; k++) if (e0 + k < S) idx_out[e0 + k] = wv[k];
        }
    }
}

// ---- single-wave downsample for S<=64 (tail levels): shfl scan, no LDS ----
// Executed by threads t<64 only (caller wraps + syncs). Sole writer of cnt_out.
__device__ void down_small_wave(const int* __restrict__ idx_in, int HinB,
                                int* __restrict__ idx_out, int* __restrict__ nbr_out,
                                int* __restrict__ cnt_out, int HoutB, int cap_out,
                                int zofs) {
    int t = threadIdx.x;   // < 64
    int Hout = 1 << HoutB, Hin = 1 << HinB, S = Hout * Hout;
    int p = t;
    int jv[9];
    int pr = 0;
    #pragma unroll
    for (int tap = 0; tap < 9; tap++) jv[tap] = -1;
    if (p < S) {
        int r = p >> HoutB, c = p & (Hout - 1);
        #pragma unroll
        for (int a = 0; a < 3; a++)
            #pragma unroll
            for (int b = 0; b < 3; b++) {
                int rr = 2 * r + a - 1, cc = 2 * c + b - 1;
                if ((unsigned)rr < (unsigned)Hin && (unsigned)cc < (unsigned)Hin)
                    jv[a * 3 + b] = idx_in[(rr << HinB) + cc];
            }
        pr = ((jv[4] & jv[5] & jv[7] & jv[8]) >= 0);
    }
    int scan = pr;
    #pragma unroll
    for (int d = 1; d < 64; d <<= 1) {
        int tv = __shfl_up(scan, d, 64);
        if (t >= d) scan += tv;
    }
    int myoff = scan - pr;
    int tot = __shfl(scan, 63, 64);
    if (p < S) {
        int wv = -1;
        if (pr && myoff < cap_out) {
            wv = myoff;
            #pragma unroll
            for (int tap = 0; tap < 9; tap++) {
                int j = jv[tap];
                nbr_out[myoff * 9 + tap] = (j < 0) ? zofs : (j << 7);
            }
        }
        idx_out[p] = wv;
    }
    if (t == 0 && tot) atomicAdd(cnt_out, tot);
}

// ---- small conv for tail, 1024 threads, CHUNKED (64 slots/round, n<=cap) ----
// Each chunk: all slots staged in one gather round (64 x 9 x 128 B = 72 KB
// LDS), one co per thread (wreg[9]=36 VGPR, safe under the 128-VGPR cap of
// 1024-thread blocks). r10: chunk loop lets the tail absorb conv7 (n<=256).
__device__ void conv_small_1024(const char* __restrict__ vprevb,
                                const float* __restrict__ wlvl,
                                const int* __restrict__ nbr, int n,
                                float* __restrict__ vals, float* __restrict__ poolp) {
    __shared__ __align__(16) float s_in[576 * 32];
    int t = threadIdx.x;
    int ciq = t & 7, co = (t >> 3) & 31, sp = t >> 8;   // sp in [0,4)
    float4 wreg[9];
    #pragma unroll
    for (int tap = 0; tap < 9; tap++)
        wreg[tap] = *(const float4*)(wlvl + ((tap * 32 + co) << 5) + (ciq << 2));
    float ps = 0.f;
    for (int c0 = 0; c0 < n; c0 += 64) {
        int nc = n - c0; if (nc > 64) nc = 64;
        __syncthreads();   // protect s_in reuse from previous chunk
        int items = nc * 72;   // nc*9 rows x 8 16-B chunks
        for (int i = t; i < items; i += 1024) {
            int row = i >> 3, q = i & 7;
            int jb = nbr[c0 * 9 + row];   // 8 lanes broadcast same row offset
            *(float4*)&s_in[(row << 5) + (q << 2)] =
                *(const float4*)(vprevb + jb + (q << 4));
        }
        __syncthreads();
        #pragma unroll 1
        for (int gp = 0; gp < 16; gp++) {
            int g = gp * 4 + sp;
            if (g >= nc) break;   // uniform within each wave
            float a0 = 0.f;
            #pragma unroll
            for (int tap = 0; tap < 9; tap++) {
                float4 v = *(const float4*)&s_in[((g * 9 + tap) << 5) + (ciq << 2)];
                a0 = fma4(v, wreg[tap], a0);
            }
            a0 += __shfl_xor(a0, 1); a0 += __shfl_xor(a0, 2); a0 += __shfl_xor(a0, 4);
            if (ciq == 0) {
                float r0 = fmaxf(a0, 0.f);
                vals[((size_t)(c0 + g) << 5) + co] = r0;
                ps += r0;
            }
        }
    }
    if (ciq == 0 && ps != 0.f) atomicAdd(&poolp[co], ps);
}

// ---- conv 3x3 s2 32->32: PIPELINED staging, register-j, ONE barrier/group ----
// thread = (ciq = t&7, coh = (t>>3)&15 -> co {coh, coh+16}, sp = t>>7)
// r10: j-indices live in registers jn[5] (8-lane-broadcast loads from nbr,
// prefetched TWO groups ahead) instead of an s_j LDS hop -> the per-group
// {write s_j, barrier} leg is gone. Single __syncthreads per group both
// drains the in-flight gather for s_in[cur] (vmcnt(0) at barrier, r9-proven)
// and releases s_in[cur^1] for the next GLDS issue.
__device__ void conv_bs(const char* __restrict__ vprevb, const float* __restrict__ wlvl,
                        const int* __restrict__ nbr, int n,
                        float* __restrict__ vals, float* __restrict__ poolp,
                        int b0, int nbk, int shard) {
    __shared__ __align__(16) float s_in[2][144 * 32];   // 2 x 18 KB
    int t = threadIdx.x;
    int ciq = t & 7, coh = (t >> 3) & 15, sp = t >> 7;
    int wid = t >> 6, lrow = (t >> 3) & 7, lq = t & 7;
    float4 wreg[9][2];
    #pragma unroll
    for (int tap = 0; tap < 9; tap++) {
        wreg[tap][0] = *(const float4*)(wlvl + ((tap * 32 + coh) << 5) + (ciq << 2));
        wreg[tap][1] = *(const float4*)(wlvl + ((tap * 32 + coh + 16) << 5) + (ciq << 2));
    }
    float ps0 = 0.f, ps1 = 0.f;
    int ngr = (n + 15) >> 4;
    int n9 = n * 9;

    int jn[5];
    // j for first group -> issue its gather into s_in[0]
    #pragma unroll
    for (int inst = 0; inst < 5; inst++) {
        int ii = wid + inst * 4;
        int gi = b0 * 144 + ii * 8 + lrow;
        jn[inst] = (b0 < ngr && ii < 18 && gi < n9) ? nbr[gi] : 0;
    }
    if (b0 < ngr) {
        #pragma unroll
        for (int inst = 0; inst < 5; inst++) {
            int ii = wid + inst * 4;
            if (ii < 18)
                GLDS16(vprevb + jn[inst] + (lq << 4), &s_in[0][ii << 8]);
        }
    }
    {   // prefetch j for the second group
        int g1 = b0 + nbk;
        #pragma unroll
        for (int inst = 0; inst < 5; inst++) {
            int ii = wid + inst * 4;
            int gi = g1 * 144 + ii * 8 + lrow;
            jn[inst] = (g1 < ngr && ii < 18 && gi < n9) ? nbr[gi] : 0;
        }
    }

    int cur = 0;
    for (int grp = b0; grp < ngr; grp += nbk) {
        __syncthreads();   // drain gather for s_in[cur]; all waves done with s_in[cur^1]
        if (grp + nbk < ngr) {
            float* dst = s_in[cur ^ 1];
            #pragma unroll
            for (int inst = 0; inst < 5; inst++) {
                int ii = wid + inst * 4;
                if (ii < 18)
                    GLDS16(vprevb + jn[inst] + (lq << 4), &dst[ii << 8]);
            }
        }
        {   // prefetch j two groups ahead
            int g2 = grp + 2 * nbk;
            #pragma unroll
            for (int inst = 0; inst < 5; inst++) {
                int ii = wid + inst * 4;
                int gi = g2 * 144 + ii * 8 + lrow;
                jn[inst] = (g2 < ngr && ii < 18 && gi < n9) ? nbr[gi] : 0;
            }
        }
        // compute from s_in[cur] (overlaps the in-flight gather for g+1)
        const float* sb = s_in[cur];
        #pragma unroll
        for (int gp = 0; gp < 8; gp++) {
            int g = gp * 2 + sp;
            int s = (grp << 4) + g;
            float4 v[9];
            #pragma unroll
            for (int tap = 0; tap < 9; tap++)
                v[tap] = *(const float4*)&sb[((g * 9 + tap) << 5) + (ciq << 2)];
            float a0 = 0.f, a1 = 0.f;
            #pragma unroll
            for (int tap = 0; tap < 9; tap++) {
                a0 = fma4(v[tap], wreg[tap][0], a0);
                a1 = fma4(v[tap], wreg[tap][1], a1);
            }
            a0 += __shfl_xor(a0, 1); a0 += __shfl_xor(a0, 2); a0 += __shfl_xor(a0, 4);
            a1 += __shfl_xor(a1, 1); a1 += __shfl_xor(a1, 2); a1 += __shfl_xor(a1, 4);
            if (ciq == 0 && s < n) {
                float r0 = fmaxf(a0, 0.f), r1 = fmaxf(a1, 0.f);
                vals[((size_t)s << 5) + coh] = r0;
                vals[((size_t)s << 5) + coh + 16] = r1;
                ps0 += r0; ps1 += r1;
            }
        }
        cur ^= 1;
    }
    if (ciq == 0 && (ps0 != 0.f || ps1 != 0.f)) {
        atomicAdd(&poolp[shard * 448 + coh], ps0);
        atomicAdd(&poolp[shard * 448 + coh + 16], ps1);
    }
}

// ---- conv0 (5x5, cin=1): LDS-staged windows, folded pool ----
__device__ void conv0_bs(const float* __restrict__ x, const float* __restrict__ w1,
                         const int* __restrict__ coords0, int n,
                         float* __restrict__ vals0, float* __restrict__ poolp,
                         int b0, int nbk, int shard) {
    __shared__ float lw[800];
    __shared__ float lx[8][28];
    __shared__ float red[256];
    int t = threadIdx.x;
    for (int i = t; i < 800; i += 256) lw[i] = w1[i];
    int sl = t >> 5, ch = t & 31;
    float psum = 0.f;
    int ngr = (n + 7) >> 3;
    for (int grp = b0; grp < ngr; grp += nbk) {
        __syncthreads();
        if (t < 200) {
            int slot = t / 25, tap = t - slot * 25;
            int s = (grp << 3) + slot;
            float v = 0.f;
            if (s < n) {
                int p = coords0[s];
                int r = p >> 11, c = p & 2047;
                int a = tap / 5, b = tap - a * 5;
                int rr = r + a - 2, cc = c + b - 2;
                if ((unsigned)rr < 2048u && (unsigned)cc < 2048u)
                    v = x[(rr << 11) + cc];
            }
            lx[slot][tap] = v;
        }
        __syncthreads();
        int s = (grp << 3) + sl;
        float acc = 0.f;
        #pragma unroll
        for (int tap = 0; tap < 25; tap++)
            acc = fmaf(lx[sl][tap], lw[tap * 32 + ch], acc);
        if (s < n) {
            float r0 = fmaxf(acc, 0.f);
            vals0[((size_t)s << 5) + ch] = r0;
            psum += r0;
        }
    }
    __syncthreads();
    red[t] = psum;
    __syncthreads();
    if (t < 32) {
        float tot = 0.f;
        #pragma unroll
        for (int q = 0; q < 8; q++) tot += red[t + 32 * q];
        if (tot != 0.f) atomicAdd(&poolp[shard * 448 + t], tot);
    }
}

// F0 = compaction (0..1023) + weight transpose (1024..1491) + zero-rows (1492)
__global__ __launch_bounds__(256) void k_f0(
    const float4* __restrict__ mask4, int* __restrict__ idxmap,
    int* __restrict__ coords, int* __restrict__ cnt, int cap,
    const float* __restrict__ w, float* __restrict__ wt,
    char* __restrict__ wsbase, ZeroArgs za) {
    if (blockIdx.x == 1492) {
        for (int i = threadIdx.x; i < 13 * 32; i += 256)
            *(float*)(wsbase + za.zoff[i >> 5] + ((i & 31) << 2)) = 0.f;
        return;
    }
    if (blockIdx.x >= 1024) {
        int t = (int)(blockIdx.x - 1024) * 256 + threadIdx.x;
        if (t < 13 * 9 * 32 * 32) {
            int ci = t & 31, co = (t >> 5) & 31, tp = t >> 10;
            wt[(tp << 10) + (co << 5) + ci] = w[(tp << 10) + (ci << 5) + co];
        }
        return;
    }
    compact0_tile(mask4, idxmap, coords, cnt, cap, blockIdx.x);
}

// F1 = down1+nbr1 (0..1023) + conv0 (1024..5119) + wm warm (5120..5143)
__global__ __launch_bounds__(256) void k_f1(
    const int* __restrict__ idx0, int* __restrict__ idx1, int* __restrict__ nbr1,
    int* __restrict__ cnt1, int cap1, int zofs1,
    const float* __restrict__ x, const float* __restrict__ w1,
    const int* __restrict__ coords0, const int* __restrict__ cnt0, int cap0,
    float* __restrict__ vals0, float* __restrict__ poolp,
    const float* __restrict__ wm1, const float* __restrict__ wm2, float* __restrict__ dummy) {
    if (blockIdx.x < 1024) {
        down_nbr(idx0, 11, idx1, nbr1, cnt1, 10, cap1, zofs1, blockIdx.x);
        return;
    }
    if (blockIdx.x >= 5120) {
        int t = (int)(blockIdx.x - 5120) * 256 + threadIdx.x;
        const float4* a = (const float4*)wm1;
        const float4* b = (const float4*)wm2;
        float acc = 0.f;
        for (int i = t; i < 28672; i += 6144) { float4 v = a[i]; acc += v.x + v.y + v.z + v.w; }
        for (int i = t; i < 8192; i += 6144)  { float4 v = b[i]; acc += v.x + v.y + v.z + v.w; }
        if (acc == 1234.56789f) dummy[0] = acc;
        return;
    }
    int n = *cnt0; if (n > cap0) n = cap0;
    conv0_bs(x, w1, coords0, n, vals0, poolp, blockIdx.x - 1024, 4096, blockIdx.x & (NSHARD - 1));
}

// F_i (i=2..7): down_i (+nbr_i) fused with conv_{i-1} (+pool_{i-1})
__global__ __launch_bounds__(256) void k_flevel(
    int downB,
    const int* __restrict__ idx_in, int HinB,
    int* __restrict__ idx_out, int* __restrict__ nbr_out, int* __restrict__ cnt_out,
    int HoutB, int cap_out, int zofs,
    const char* __restrict__ vprevb, const float* __restrict__ wlvl,
    const int* __restrict__ nbr_c, const int* __restrict__ cnt_c, int cap_c,
    float* __restrict__ vals_c, float* __restrict__ poolp) {
    if ((int)blockIdx.x < downB) {
        down_nbr(idx_in, HinB, idx_out, nbr_out, cnt_out, HoutB, cap_out, zofs, blockIdx.x);
        return;
    }
    int n = *cnt_c; if (n > cap_c) n = cap_c;
    conv_bs(vprevb, wlvl, nbr_c, n, vals_c, poolp,
            blockIdx.x - downB, gridDim.x - downB, blockIdx.x & (NSHARD - 1));
}

// TAIL4: down8 + conv7 + down9 + conv8 + down10 + conv9 + conv10..13 + feat
// + MLP at 1024 threads. r10: absorbs flevel i=8 (conv7 n<=256 runs as 4
// chunked conv_small rounds; cheaper than a dispatch+drain cycle).
__global__ __launch_bounds__(1024) void k_tail4(TailArgs a) {
    char* ws = a.ws;
    int* cnt = (int*)ws;
    float* poolsh = (float*)(ws + 256);
    float* wt = (float*)(ws + 32768);
    int t = threadIdx.x;

    // down8: idx7 (H=16) -> idx8 (H=8), nbr8 (into vals7), cnt8  [wave 0]
    if (t < 64)
        down_small_wave((const int*)(ws + a.idx7), 4, (int*)(ws + a.idx8),
                        (int*)(ws + a.nbr8), cnt + 8, 3, a.cap8, a.cap7 * 128);
    __syncthreads();
    // conv7: vals6 -> vals7 (n7 from previous kernel's down7)
    {
        int n7 = cnt_load(cnt + 7); if (n7 > a.cap7) n7 = a.cap7;
        conv_small_1024((const char*)(ws + a.val6), wt + (size_t)6 * 9216,
                        (const int*)(ws + a.nbr7), n7,
                        (float*)(ws + a.val7), poolsh + 7 * 32);
    }
    __syncthreads();
    // down9: idx8 (H=8) -> idx9 (H=4), nbr9 (into vals8), cnt9  [wave 0]
    if (t < 64)
        down_small_wave((const int*)(ws + a.idx8), 3, (int*)(ws + a.idx9),
                        (int*)(ws + a.nbr9), cnt + 9, 2, a.cap9, a.cap8 * 128);
    __syncthreads();
    // conv8: vals7 -> vals8 (n8 written by down8 in THIS kernel -> cnt_load)
    {
        int n8 = cnt_load(cnt + 8); if (n8 > a.cap8) n8 = a.cap8;
        conv_small_1024((const char*)(ws + a.val7), wt + (size_t)7 * 9216,
                        (const int*)(ws + a.nbr8), n8,
                        (float*)(ws + a.val8), poolsh + 8 * 32);
    }
    __syncthreads();
    // down10: idx9 (H=4) -> idx10 (H=2), nbr10 (into vals9), cnt10  [wave 0]
    if (t < 64)
        down_small_wave((const int*)(ws + a.idx9), 2, (int*)(ws + a.idx10),
                        (int*)(ws + a.nbr10), cnt + 10, 1, a.cap10, a.cap9 * 128);
    __syncthreads();
    // conv9: vals8 -> vals9 (n9 written by down9 in THIS kernel -> cnt_load)
    {
        int n9 = cnt_load(cnt + 9); if (n9 > a.cap9) n9 = a.cap9;
        conv_small_1024((const char*)(ws + a.val8), wt + (size_t)8 * 9216,
                        (const int*)(ws + a.nbr9), n9,
                        (float*)(ws + a.val9), poolsh + 9 * 32);
    }
    __syncthreads();

    // ---- conv10..13 + feat + MLP: proven 1024-thread body ----
    const char* vals9b = (const char*)(ws + a.val9);
    const int* nbr10 = (const int*)(ws + a.nbr10);
    const int* idx10 = (const int*)(ws + a.idx10);
    __shared__ __align__(16) float v10[128];
    __shared__ float v11[32], v12[32], v13[32];
    __shared__ float feat[448], h[256], part[1024];
    __shared__ int s_i10[4], s_n10;
    int ciq = t & 7, co = (t >> 3) & 31, s = t >> 8;
    int ciq16 = ciq << 4;
    if (t == 0) s_n10 = cnt_load(cnt + 10);
    if (t < 4) s_i10[t] = idx10[t];
    __syncthreads();
    int n10 = s_n10; if (n10 > 4) n10 = 4;
    {   // conv10: 4 slot-groups x 256 threads, byte-offset gather (zero-row padded)
        const float* wl = wt + (size_t)9 * 9216;
        float4 wreg[9];
        #pragma unroll
        for (int tap = 0; tap < 9; tap++)
            wreg[tap] = *(const float4*)(wl + ((tap * 32 + co) << 5) + (ciq << 2));
        bool live = s < n10;
        int sb = live ? s : 0;
        float a0 = 0.f;
        #pragma unroll
        for (int tap = 0; tap < 9; tap++)
            a0 = fma4(*(const float4*)(vals9b + nbr10[sb * 9 + tap] + ciq16), wreg[tap], a0);
        a0 += __shfl_xor(a0, 1); a0 += __shfl_xor(a0, 2); a0 += __shfl_xor(a0, 4);
        if (ciq == 0 && live) v10[s * 32 + co] = fmaxf(a0, 0.f);
    }
    __syncthreads();
    int i10[4] = {s_i10[0], s_i10[1], s_i10[2], s_i10[3]};
    int nbr11[9];
    #pragma unroll
    for (int tap = 0; tap < 9; tap++) {
        int aa = tap / 3, bb = tap - aa * 3;
        int rr = aa - 1, cc = bb - 1;
        nbr11[tap] = ((unsigned)rr < 2u && (unsigned)cc < 2u) ? i10[rr * 2 + cc] : -1;
    }
    int n11 = ((nbr11[4] & nbr11[5] & nbr11[7] & nbr11[8]) >= 0) ? 1 : 0;
    if (s == 0) {   // conv11 from LDS v10
        const float* wl = wt + (size_t)10 * 9216;
        float a0 = 0.f;
        #pragma unroll
        for (int tap = 0; tap < 9; tap++) {
            int j = nbr11[tap];
            if (j >= 0) {
                float4 wv = *(const float4*)(wl + ((tap * 32 + co) << 5) + (ciq << 2));
                a0 = fma4(*(const float4*)(&v10[(j << 5) + (ciq << 2)]), wv, a0);
            }
        }
        a0 += __shfl_xor(a0, 1); a0 += __shfl_xor(a0, 2); a0 += __shfl_xor(a0, 4);
        if (ciq == 0) v11[co] = n11 ? fmaxf(a0, 0.f) : 0.f;
    }
    __syncthreads();
    if (s == 0) {   // conv12: center tap only
        const float* wl = wt + (size_t)11 * 9216;
        float4 wv = *(const float4*)(wl + ((4 * 32 + co) << 5) + (ciq << 2));
        float a0 = n11 ? fma4(*(const float4*)(&v11[ciq << 2]), wv, 0.f) : 0.f;
        a0 += __shfl_xor(a0, 1); a0 += __shfl_xor(a0, 2); a0 += __shfl_xor(a0, 4);
        if (ciq == 0) v12[co] = n11 ? fmaxf(a0, 0.f) : 0.f;
    }
    __syncthreads();
    if (s == 0) {   // conv13
        const float* wl = wt + (size_t)12 * 9216;
        float4 wv = *(const float4*)(wl + ((4 * 32 + co) << 5) + (ciq << 2));
        float a0 = n11 ? fma4(*(const float4*)(&v12[ciq << 2]), wv, 0.f) : 0.f;
        a0 += __shfl_xor(a0, 1); a0 += __shfl_xor(a0, 2); a0 += __shfl_xor(a0, 4);
        if (ciq == 0) v13[co] = n11 ? fmaxf(a0, 0.f) : 0.f;
    }
    __syncthreads();
    // feat assembly: levels 0..9 from pool shards, 10..13 from LDS
    if (t < 320) {
        float sum = 0.f;
        #pragma unroll
        for (int sh = 0; sh < NSHARD; sh++) sum += poolsh[sh * 448 + t];
        float c = (float)cnt_load(cnt + (t >> 5)); if (c < 1.f) c = 1.f;
        feat[t] = sum / c;
    }
    if (t < 32) {
        float s10 = 0.f;
        for (int q = 0; q < n10; q++) s10 += v10[q * 32 + t];
        float c10 = (float)n10; if (c10 < 1.f) c10 = 1.f;
        feat[320 + t] = s10 / c10;
        feat[352 + t] = n11 ? v11[t] : 0.f;
        feat[384 + t] = n11 ? v12[t] : 0.f;
        feat[416 + t] = n11 ? v13[t] : 0.f;
    }
    __syncthreads();
    // MLP stage 1: 448 -> 256 (4 k-chunks of 112)
    {
        int j = t & 255, chunk = t >> 8;
        float acc = (chunk == 0) ? a.bm1[j] : 0.f;
        int k0 = chunk * 112;
        #pragma unroll 8
        for (int k = k0; k < k0 + 112; k++) acc = fmaf(feat[k], a.wm1[k * 256 + j], acc);
        part[t] = acc;
    }
    __syncthreads();
    if (t < 256)
        h[t] = fmaxf(part[t] + part[t + 256] + part[t + 512] + part[t + 768], 0.f);
    __syncthreads();
    // MLP stage 2: 256 -> 128 (8 k-chunks of 32)
    {
        int j2 = t & 127, c2 = t >> 7;
        float a2 = (c2 == 0) ? a.bm2[j2] : 0.f;
        int kk0 = c2 * 32;
        #pragma unroll 8
        for (int k = kk0; k < kk0 + 32; k++) a2 = fmaf(h[k], a.wm2[k * 128 + j2], a2);
        part[t] = a2;
    }
    __syncthreads();
    if (t < 128) {
        float sum = 0.f;
        #pragma unroll
        for (int c = 0; c < 8; c++) sum += part[t + 128 * c];
        a.out[t] = sum;
    }
}

extern "C" void kernel_launch(void* const* d_in, const int* in_sizes, int n_in,
                              void* d_out, int out_size, void* d_ws, size_t ws_size,
                              hipStream_t stream) {
    const float* x    = (const float*)d_in[0];
    const float* mask = (const float*)d_in[1];
    const float* w1   = (const float*)d_in[2];
    const float* wsrc = (const float*)d_in[3];
    const float* wm1  = (const float*)d_in[4];
    const float* bm1  = (const float*)d_in[5];
    const float* wm2  = (const float*)d_in[6];
    const float* bm2  = (const float*)d_in[7];
    float* out = (float*)d_out;
    char* ws = (char*)d_ws;

    static const int Hb[NLVL]   = {11, 10, 9, 8, 7, 6, 5, 4, 3, 2, 1, 0, 0, 0};
    static const int caps[NLVL] = {45056, 43008, 43008, 34816, 16384, 4096,
                                   1024, 256, 64, 16, 4, 1, 1, 1};

    // ws layout: cnt[16]@0, dummy@128, pool shards@256 (16*448 f32), wt@32768
    size_t pool_off = 256;
    size_t wt_off = 32768;
    size_t off = wt_off + (size_t)13 * 9 * 1024 * 4;
    off = (off + 255) & ~(size_t)255;
    size_t coord0_off = off; off += (size_t)caps[0] * 4; off = (off + 255) & ~(size_t)255;
    size_t idx_off[NLVL], nbr_off[NLVL], val_off[NLVL];
    for (int l = 0; l < NLVL; l++) {
        size_t S = (size_t)(1 << Hb[l]) * (1 << Hb[l]);
        size_t sb = S * 4; if (sb < 16) sb = 16;
        idx_off[l] = off; off += sb; off = (off + 255) & ~(size_t)255;
        if (l >= 1) { nbr_off[l] = off; off += (size_t)caps[l] * 36; off = (off + 255) & ~(size_t)255; }
        else nbr_off[l] = 0;
        val_off[l] = off; off += (size_t)(caps[l] + 1) * 128; off = (off + 255) & ~(size_t)255;
    }

    int* cnt = (int*)ws;
    float* poolsh = (float*)(ws + pool_off);
    float* dummy = (float*)(ws + 128);
    float* wt = (float*)(ws + wt_off);

    ZeroArgs za;
    for (int l = 0; l < 13; l++) za.zoff[l] = val_off[l] + (size_t)caps[l] * 128;

    hipMemsetAsync(ws, 0, 32768, stream);   // cnt + pool shards

    k_f0<<<1493, 256, 0, stream>>>(
        (const float4*)mask, (int*)(ws + idx_off[0]), (int*)(ws + coord0_off),
        cnt, caps[0], wsrc, wt, ws, za);

    k_f1<<<5144, 256, 0, stream>>>(
        (const int*)(ws + idx_off[0]), (int*)(ws + idx_off[1]), (int*)(ws + nbr_off[1]),
        cnt + 1, caps[1], caps[0] * 128,
        x, w1, (const int*)(ws + coord0_off), cnt, caps[0],
        (float*)(ws + val_off[0]), poolsh, wm1, wm2, dummy);

    for (int i = 2; i <= 7; i++) {
        int lc = i - 1;
        int Hout = 1 << Hb[i];
        int S4 = (Hout * Hout + 3) >> 2;
        int downB = (S4 + 255) >> 8; if (downB < 1) downB = 1;
        // conv blocks capped at 768 (3 blocks/CU, full residency): each block
        // amortizes its weight preload + pipeline prologue over >=3.5 groups.
        int convB = (caps[lc] + 15) >> 4;
        if (convB > 768) convB = 768;
        k_flevel<<<downB + convB, 256, 0, stream>>>(
            downB,
            (const int*)(ws + idx_off[i - 1]), Hb[i - 1],
            (int*)(ws + idx_off[i]), (int*)(ws + nbr_off[i]), cnt + i, Hb[i], caps[i],
            caps[i - 1] * 128,
            (const char*)(ws + val_off[lc - 1]), wt + (size_t)(lc - 1) * 9216,
            (const int*)(ws + nbr_off[lc]), cnt + lc, caps[lc],
            (float*)(ws + val_off[lc]), poolsh + lc * 32);
    }

    TailArgs ta;
    ta.ws = ws;
    ta.wm1 = wm1; ta.bm1 = bm1; ta.wm2 = wm2; ta.bm2 = bm2;
    ta.out = out;
    ta.idx7 = idx_off[7];  ta.idx8 = idx_off[8];
    ta.idx9 = idx_off[9];  ta.idx10 = idx_off[10];
    ta.nbr7 = nbr_off[7];  ta.nbr8 = nbr_off[8];
    ta.nbr9 = nbr_off[9];  ta.nbr10 = nbr_off[10];
    ta.val6 = val_off[6];  ta.val7 = val_off[7];
    ta.val8 = val_off[8];  ta.val9 = val_off[9];
    ta.cap7 = caps[7]; ta.cap8 = caps[8]; ta.cap9 = caps[9]; ta.cap10 = caps[10];
    k_tail4<<<1, 1024, 0, stream>>>(ta);
}

// Round 11
// 252.740 us; speedup vs baseline: 1.1302x; 1.1302x over previous
//
#include <hip/hip_runtime.h>

#define NLVL 14
#define NSHARD 16

struct ZeroArgs { unsigned long long zoff[13]; };

struct TailArgs {
    char* ws;
    const float* wm1; const float* bm1;
    const float* wm2; const float* bm2;
    float* out;
    unsigned long long idx8, idx9, idx10;
    unsigned long long nbr8, nbr9, nbr10;
    unsigned long long val7, val8, val9;
    int cap8, cap9, cap10;
};

__device__ __forceinline__ float fma4(float4 v, float4 w, float acc) {
    acc = fmaf(v.x, w.x, acc);
    acc = fmaf(v.y, w.y, acc);
    acc = fmaf(v.z, w.z, acc);
    return fmaf(v.w, w.w, acc);
}

__device__ __forceinline__ int cnt_load(const int* p) {
    // agent-scope atomic load: bypasses the CU L1 so we never see a line that
    // was cached before a same-kernel atomicAdd updated it at L2.
    return __hip_atomic_load(p, __ATOMIC_RELAXED, __HIP_MEMORY_SCOPE_AGENT);
}

// async global->LDS, 16 B per lane, wave-uniform LDS base + lane*16 dest.
#define GLDS16(gsrc, ldst) __builtin_amdgcn_global_load_lds( \
    (const __attribute__((address_space(1))) void*)(gsrc),   \
    (__attribute__((address_space(3))) void*)(ldst), 16, 0, 0)

// exclusive prefix over a 256-thread block, one atomicAdd per block.
// Entry __syncthreads makes it loop/multi-call reentrant (protects wsum reuse).
__device__ __forceinline__ int block_scan_base(int mycnt, int* gcnt, int& myoff) {
    __shared__ int wsum[4];
    __shared__ int base;
    __syncthreads();
    int lane = threadIdx.x & 63, wid = threadIdx.x >> 6;
    int scan = mycnt;
    #pragma unroll
    for (int d = 1; d < 64; d <<= 1) {
        int tv = __shfl_up(scan, d, 64);
        if (lane >= d) scan += tv;
    }
    if (lane == 63) wsum[wid] = scan;
    __syncthreads();
    if (threadIdx.x == 0) {
        int tot = 0;
        #pragma unroll
        for (int i = 0; i < 4; i++) { int tv = wsum[i]; wsum[i] = tot; tot += tv; }
        base = tot ? atomicAdd(gcnt, tot) : 0;
    }
    __syncthreads();
    myoff = wsum[wid] + scan - mycnt;
    return base;
}

// ---- level-0 mask compaction tile ----
__device__ void compact0_tile(const float4* __restrict__ mask4, int* __restrict__ idxmap,
                              int* __restrict__ coords, int* __restrict__ cnt, int cap, int tile) {
    int t = threadIdx.x;
    int g0 = tile * 1024 + t;
    float4 m[4];
    #pragma unroll
    for (int j = 0; j < 4; j++) m[j] = mask4[g0 + j * 256];
    int pr[16];
    int mycnt = 0;
    #pragma unroll
    for (int j = 0; j < 4; j++) {
        pr[4 * j + 0] = m[j].x > 0.5f;
        pr[4 * j + 1] = m[j].y > 0.5f;
        pr[4 * j + 2] = m[j].z > 0.5f;
        pr[4 * j + 3] = m[j].w > 0.5f;
        mycnt += pr[4 * j] + pr[4 * j + 1] + pr[4 * j + 2] + pr[4 * j + 3];
    }
    int myoff;
    int base = block_scan_base(mycnt, cnt, myoff);
    int slot = base + myoff;
    #pragma unroll
    for (int j = 0; j < 4; j++) {
        int e0 = (g0 + j * 256) << 2;
        int wv[4];
        #pragma unroll
        for (int k = 0; k < 4; k++) {
            wv[k] = -1;
            if (pr[4 * j + k]) {
                int sl = slot++;
                if (sl < cap) { wv[k] = sl; coords[sl] = e0 + k; }
            }
        }
        *(int4*)(idxmap + e0) = make_int4(wv[0], wv[1], wv[2], wv[3]);
    }
}

// ---- downsample + neighbor lists (byte offsets into vals_{l-1}, zero-row remap) ----
__device__ void down_nbr(const int* __restrict__ idx_in, int HinB,
                         int* __restrict__ idx_out, int* __restrict__ nbr_out,
                         int* __restrict__ cnt_out, int HoutB, int cap_out,
                         int zofs, int bb) {
    int Hout = 1 << HoutB, Hin = 1 << HinB;
    int S = Hout * Hout;
    int S4 = (S + 3) >> 2;
    int o4 = bb * 256 + threadIdx.x;
    int e0 = o4 << 2;
    int jv[4][9];
    int pr[4] = {0, 0, 0, 0};
    #pragma unroll
    for (int k = 0; k < 4; k++)
        #pragma unroll
        for (int tap = 0; tap < 9; tap++) jv[k][tap] = -1;
    if (o4 < S4) {
        if (HoutB >= 2) {
            int r = e0 >> HoutB, c0 = e0 & (Hout - 1);
            int w[3][12];
            #pragma unroll
            for (int a = 0; a < 3; a++) {
                int rr = 2 * r + a - 1;
                bool rok = (unsigned)rr < (unsigned)Hin;
                const int* rowp = idx_in + ((size_t)(rok ? rr : 0) << HinB) + 2 * c0;
                int4 L = (rok && c0 > 0) ? *(const int4*)(rowp - 4) : make_int4(-1, -1, -1, -1);
                int4 M = rok ? *(const int4*)rowp : make_int4(-1, -1, -1, -1);
                int4 R = rok ? *(const int4*)(rowp + 4) : make_int4(-1, -1, -1, -1);
                w[a][0] = L.x; w[a][1] = L.y; w[a][2]  = L.z; w[a][3]  = L.w;
                w[a][4] = M.x; w[a][5] = M.y; w[a][6]  = M.z; w[a][7]  = M.w;
                w[a][8] = R.x; w[a][9] = R.y; w[a][10] = R.z; w[a][11] = R.w;
            }
            #pragma unroll
            for (int k = 0; k < 4; k++) {
                #pragma unroll
                for (int a = 0; a < 3; a++)
                    #pragma unroll
                    for (int b = 0; b < 3; b++)
                        jv[k][a * 3 + b] = w[a][2 * k + b + 3];
                pr[k] = ((jv[k][4] & jv[k][5] & jv[k][7] & jv[k][8]) >= 0);
            }
        } else {   // Hout 1 or 2 (scalar path)
            #pragma unroll
            for (int k = 0; k < 4; k++) {
                int p = e0 + k;
                if (p < S) {
                    int r = p >> HoutB, c = p & (Hout - 1);
                    #pragma unroll
                    for (int a = 0; a < 3; a++)
                        #pragma unroll
                        for (int b = 0; b < 3; b++) {
                            int rr = 2 * r + a - 1, cc = 2 * c + b - 1;
                            if ((unsigned)rr < (unsigned)Hin && (unsigned)cc < (unsigned)Hin)
                                jv[k][a * 3 + b] = idx_in[((size_t)rr << HinB) + cc];
                        }
                    pr[k] = ((jv[k][4] & jv[k][5] & jv[k][7] & jv[k][8]) >= 0);
                }
            }
        }
    }
    int mycnt = pr[0] + pr[1] + pr[2] + pr[3];
    int myoff;
    int base = block_scan_base(mycnt, cnt_out, myoff);
    int slot = base + myoff;
    int wv[4] = {-1, -1, -1, -1};
    #pragma unroll
    for (int k = 0; k < 4; k++) {
        if (pr[k]) {
            int sl = slot++;
            if (sl < cap_out) {
                wv[k] = sl;
                #pragma unroll
                for (int tap = 0; tap < 9; tap++) {
                    int j = jv[k][tap];
                    nbr_out[sl * 9 + tap] = (j < 0) ? zofs : (j << 7);
                }
            }
        }
    }
    if (o4 < S4) {
        if (S >= 4) *(int4*)(idx_out + e0) = make_int4(wv[0], wv[1], wv[2], wv[3]);
        else {
            #pragma unroll
            for (int k = 0; k < 4; k++) if (e0 + k < S) idx_out[e0 + k] = wv[k];
        }
    }
}

// ---- single-wave downsample for S<=64 (tail levels): shfl scan, no LDS ----
// Executed by threads t<64 only (caller wraps + syncs). Sole writer of cnt_out.
__device__ void down_small_wave(const int* __restrict__ idx_in, int HinB,
                                int* __restrict__ idx_out, int* __restrict__ nbr_out,
                                int* __restrict__ cnt_out, int HoutB, int cap_out,
                                int zofs) {
    int t = threadIdx.x;   // < 64
    int Hout = 1 << HoutB, Hin = 1 << HinB, S = Hout * Hout;
    int p = t;
    int jv[9];
    int pr = 0;
    #pragma unroll
    for (int tap = 0; tap < 9; tap++) jv[tap] = -1;
    if (p < S) {
        int r = p >> HoutB, c = p & (Hout - 1);
        #pragma unroll
        for (int a = 0; a < 3; a++)
            #pragma unroll
            for (int b = 0; b < 3; b++) {
                int rr = 2 * r + a - 1, cc = 2 * c + b - 1;
                if ((unsigned)rr < (unsigned)Hin && (unsigned)cc < (unsigned)Hin)
                    jv[a * 3 + b] = idx_in[(rr << HinB) + cc];
            }
        pr = ((jv[4] & jv[5] & jv[7] & jv[8]) >= 0);
    }
    int scan = pr;
    #pragma unroll
    for (int d = 1; d < 64; d <<= 1) {
        int tv = __shfl_up(scan, d, 64);
        if (t >= d) scan += tv;
    }
    int myoff = scan - pr;
    int tot = __shfl(scan, 63, 64);
    if (p < S) {
        int wv = -1;
        if (pr && myoff < cap_out) {
            wv = myoff;
            #pragma unroll
            for (int tap = 0; tap < 9; tap++) {
                int j = jv[tap];
                nbr_out[myoff * 9 + tap] = (j < 0) ? zofs : (j << 7);
            }
        }
        idx_out[p] = wv;
    }
    if (t == 0 && tot) atomicAdd(cnt_out, tot);
}

// ---- small conv for tail (n<=64 slots), 1024 threads ----
// All slots staged in ONE gather round (<=576 rows x 128 B = 72 KB LDS), then
// one co per thread (wreg[9]=36 VGPR, safe under the 128-VGPR cap of
// 1024-thread blocks). NOTE (r10 lesson): do NOT extend this to n>64 via
// serial chunking in a single-block kernel — absorbing conv7 (n<=256) made
// the tail 75us @ 0.18% VALUBusy (+40us total). Work >64 slots belongs in a
// multi-block flevel dispatch.
__device__ void conv_small_1024(const char* __restrict__ vprevb,
                                const float* __restrict__ wlvl,
                                const int* __restrict__ nbr, int n,
                                float* __restrict__ vals, float* __restrict__ poolp) {
    __shared__ __align__(16) float s_in[576 * 32];
    int t = threadIdx.x;
    int ciq = t & 7, co = (t >> 3) & 31, sp = t >> 8;   // sp in [0,4)
    float4 wreg[9];
    #pragma unroll
    for (int tap = 0; tap < 9; tap++)
        wreg[tap] = *(const float4*)(wlvl + ((tap * 32 + co) << 5) + (ciq << 2));
    int items = n * 72;   // n*9 rows x 8 16-B chunks
    for (int i = t; i < items; i += 1024) {
        int row = i >> 3, q = i & 7;
        int jb = nbr[row];   // 8 lanes broadcast same row offset
        *(float4*)&s_in[(row << 5) + (q << 2)] =
            *(const float4*)(vprevb + jb + (q << 4));
    }
    __syncthreads();
    float ps = 0.f;
    #pragma unroll 1
    for (int gp = 0; gp < 16; gp++) {
        int g = gp * 4 + sp;
        if (g >= n) break;   // uniform within each wave
        float a0 = 0.f;
        #pragma unroll
        for (int tap = 0; tap < 9; tap++) {
            float4 v = *(const float4*)&s_in[((g * 9 + tap) << 5) + (ciq << 2)];
            a0 = fma4(v, wreg[tap], a0);
        }
        a0 += __shfl_xor(a0, 1); a0 += __shfl_xor(a0, 2); a0 += __shfl_xor(a0, 4);
        if (ciq == 0) {
            float r0 = fmaxf(a0, 0.f);
            vals[((size_t)g << 5) + co] = r0;
            ps += r0;
        }
    }
    if (ciq == 0 && ps != 0.f) atomicAdd(&poolp[co], ps);
}

// ---- conv 3x3 s2 32->32: PIPELINED staging, register-j, ONE barrier/group ----
// thread = (ciq = t&7, coh = (t>>3)&15 -> co {coh, coh+16}, sp = t>>7)
// j-indices live in registers jn[5] (8-lane-broadcast loads from nbr,
// prefetched TWO groups ahead); no s_j LDS hop. Single __syncthreads per
// group both drains the in-flight gather for s_in[cur] (vmcnt(0) at barrier)
// and releases s_in[cur^1] for the next GLDS issue. Verified r10 (absmax 0).
__device__ void conv_bs(const char* __restrict__ vprevb, const float* __restrict__ wlvl,
                        const int* __restrict__ nbr, int n,
                        float* __restrict__ vals, float* __restrict__ poolp,
                        int b0, int nbk, int shard) {
    __shared__ __align__(16) float s_in[2][144 * 32];   // 2 x 18 KB
    int t = threadIdx.x;
    int ciq = t & 7, coh = (t >> 3) & 15, sp = t >> 7;
    int wid = t >> 6, lrow = (t >> 3) & 7, lq = t & 7;
    float4 wreg[9][2];
    #pragma unroll
    for (int tap = 0; tap < 9; tap++) {
        wreg[tap][0] = *(const float4*)(wlvl + ((tap * 32 + coh) << 5) + (ciq << 2));
        wreg[tap][1] = *(const float4*)(wlvl + ((tap * 32 + coh + 16) << 5) + (ciq << 2));
    }
    float ps0 = 0.f, ps1 = 0.f;
    int ngr = (n + 15) >> 4;
    int n9 = n * 9;

    int jn[5];
    // j for first group -> issue its gather into s_in[0]
    #pragma unroll
    for (int inst = 0; inst < 5; inst++) {
        int ii = wid + inst * 4;
        int gi = b0 * 144 + ii * 8 + lrow;
        jn[inst] = (b0 < ngr && ii < 18 && gi < n9) ? nbr[gi] : 0;
    }
    if (b0 < ngr) {
        #pragma unroll
        for (int inst = 0; inst < 5; inst++) {
            int ii = wid + inst * 4;
            if (ii < 18)
                GLDS16(vprevb + jn[inst] + (lq << 4), &s_in[0][ii << 8]);
        }
    }
    {   // prefetch j for the second group
        int g1 = b0 + nbk;
        #pragma unroll
        for (int inst = 0; inst < 5; inst++) {
            int ii = wid + inst * 4;
            int gi = g1 * 144 + ii * 8 + lrow;
            jn[inst] = (g1 < ngr && ii < 18 && gi < n9) ? nbr[gi] : 0;
        }
    }

    int cur = 0;
    for (int grp = b0; grp < ngr; grp += nbk) {
        __syncthreads();   // drain gather for s_in[cur]; all waves done with s_in[cur^1]
        if (grp + nbk < ngr) {
            float* dst = s_in[cur ^ 1];
            #pragma unroll
            for (int inst = 0; inst < 5; inst++) {
                int ii = wid + inst * 4;
                if (ii < 18)
                    GLDS16(vprevb + jn[inst] + (lq << 4), &dst[ii << 8]);
            }
        }
        {   // prefetch j two groups ahead
            int g2 = grp + 2 * nbk;
            #pragma unroll
            for (int inst = 0; inst < 5; inst++) {
                int ii = wid + inst * 4;
                int gi = g2 * 144 + ii * 8 + lrow;
                jn[inst] = (g2 < ngr && ii < 18 && gi < n9) ? nbr[gi] : 0;
            }
        }
        // compute from s_in[cur] (overlaps the in-flight gather for g+1)
        const float* sb = s_in[cur];
        #pragma unroll
        for (int gp = 0; gp < 8; gp++) {
            int g = gp * 2 + sp;
            int s = (grp << 4) + g;
            float4 v[9];
            #pragma unroll
            for (int tap = 0; tap < 9; tap++)
                v[tap] = *(const float4*)&sb[((g * 9 + tap) << 5) + (ciq << 2)];
            float a0 = 0.f, a1 = 0.f;
            #pragma unroll
            for (int tap = 0; tap < 9; tap++) {
                a0 = fma4(v[tap], wreg[tap][0], a0);
                a1 = fma4(v[tap], wreg[tap][1], a1);
            }
            a0 += __shfl_xor(a0, 1); a0 += __shfl_xor(a0, 2); a0 += __shfl_xor(a0, 4);
            a1 += __shfl_xor(a1, 1); a1 += __shfl_xor(a1, 2); a1 += __shfl_xor(a1, 4);
            if (ciq == 0 && s < n) {
                float r0 = fmaxf(a0, 0.f), r1 = fmaxf(a1, 0.f);
                vals[((size_t)s << 5) + coh] = r0;
                vals[((size_t)s << 5) + coh + 16] = r1;
                ps0 += r0; ps1 += r1;
            }
        }
        cur ^= 1;
    }
    if (ciq == 0 && (ps0 != 0.f || ps1 != 0.f)) {
        atomicAdd(&poolp[shard * 448 + coh], ps0);
        atomicAdd(&poolp[shard * 448 + coh + 16], ps1);
    }
}

// ---- conv0 (5x5, cin=1): LDS-staged windows, folded pool ----
__device__ void conv0_bs(const float* __restrict__ x, const float* __restrict__ w1,
                         const int* __restrict__ coords0, int n,
                         float* __restrict__ vals0, float* __restrict__ poolp,
                         int b0, int nbk, int shard) {
    __shared__ float lw[800];
    __shared__ float lx[8][28];
    __shared__ float red[256];
    int t = threadIdx.x;
    for (int i = t; i < 800; i += 256) lw[i] = w1[i];
    int sl = t >> 5, ch = t & 31;
    float psum = 0.f;
    int ngr = (n + 7) >> 3;
    for (int grp = b0; grp < ngr; grp += nbk) {
        __syncthreads();
        if (t < 200) {
            int slot = t / 25, tap = t - slot * 25;
            int s = (grp << 3) + slot;
            float v = 0.f;
            if (s < n) {
                int p = coords0[s];
                int r = p >> 11, c = p & 2047;
                int a = tap / 5, b = tap - a * 5;
                int rr = r + a - 2, cc = c + b - 2;
                if ((unsigned)rr < 2048u && (unsigned)cc < 2048u)
                    v = x[(rr << 11) + cc];
            }
            lx[slot][tap] = v;
        }
        __syncthreads();
        int s = (grp << 3) + sl;
        float acc = 0.f;
        #pragma unroll
        for (int tap = 0; tap < 25; tap++)
            acc = fmaf(lx[sl][tap], lw[tap * 32 + ch], acc);
        if (s < n) {
            float r0 = fmaxf(acc, 0.f);
            vals0[((size_t)s << 5) + ch] = r0;
            psum += r0;
        }
    }
    __syncthreads();
    red[t] = psum;
    __syncthreads();
    if (t < 32) {
        float tot = 0.f;
        #pragma unroll
        for (int q = 0; q < 8; q++) tot += red[t + 32 * q];
        if (tot != 0.f) atomicAdd(&poolp[shard * 448 + t], tot);
    }
}

// F0 = compaction (0..1023) + weight transpose (1024..1491) + zero-rows (1492)
__global__ __launch_bounds__(256) void k_f0(
    const float4* __restrict__ mask4, int* __restrict__ idxmap,
    int* __restrict__ coords, int* __restrict__ cnt, int cap,
    const float* __restrict__ w, float* __restrict__ wt,
    char* __restrict__ wsbase, ZeroArgs za) {
    if (blockIdx.x == 1492) {
        for (int i = threadIdx.x; i < 13 * 32; i += 256)
            *(float*)(wsbase + za.zoff[i >> 5] + ((i & 31) << 2)) = 0.f;
        return;
    }
    if (blockIdx.x >= 1024) {
        int t = (int)(blockIdx.x - 1024) * 256 + threadIdx.x;
        if (t < 13 * 9 * 32 * 32) {
            int ci = t & 31, co = (t >> 5) & 31, tp = t >> 10;
            wt[(tp << 10) + (co << 5) + ci] = w[(tp << 10) + (ci << 5) + co];
        }
        return;
    }
    compact0_tile(mask4, idxmap, coords, cnt, cap, blockIdx.x);
}

// F1 = down1+nbr1 (0..1023) + conv0 (1024..5119) + wm warm (5120..5143)
__global__ __launch_bounds__(256) void k_f1(
    const int* __restrict__ idx0, int* __restrict__ idx1, int* __restrict__ nbr1,
    int* __restrict__ cnt1, int cap1, int zofs1,
    const float* __restrict__ x, const float* __restrict__ w1,
    const int* __restrict__ coords0, const int* __restrict__ cnt0, int cap0,
    float* __restrict__ vals0, float* __restrict__ poolp,
    const float* __restrict__ wm1, const float* __restrict__ wm2, float* __restrict__ dummy) {
    if (blockIdx.x < 1024) {
        down_nbr(idx0, 11, idx1, nbr1, cnt1, 10, cap1, zofs1, blockIdx.x);
        return;
    }
    if (blockIdx.x >= 5120) {
        int t = (int)(blockIdx.x - 5120) * 256 + threadIdx.x;
        const float4* a = (const float4*)wm1;
        const float4* b = (const float4*)wm2;
        float acc = 0.f;
        for (int i = t; i < 28672; i += 6144) { float4 v = a[i]; acc += v.x + v.y + v.z + v.w; }
        for (int i = t; i < 8192; i += 6144)  { float4 v = b[i]; acc += v.x + v.y + v.z + v.w; }
        if (acc == 1234.56789f) dummy[0] = acc;
        return;
    }
    int n = *cnt0; if (n > cap0) n = cap0;
    conv0_bs(x, w1, coords0, n, vals0, poolp, blockIdx.x - 1024, 4096, blockIdx.x & (NSHARD - 1));
}

// F_i (i=2..8): down_i (+nbr_i) fused with conv_{i-1} (+pool_{i-1})
__global__ __launch_bounds__(256) void k_flevel(
    int downB,
    const int* __restrict__ idx_in, int HinB,
    int* __restrict__ idx_out, int* __restrict__ nbr_out, int* __restrict__ cnt_out,
    int HoutB, int cap_out, int zofs,
    const char* __restrict__ vprevb, const float* __restrict__ wlvl,
    const int* __restrict__ nbr_c, const int* __restrict__ cnt_c, int cap_c,
    float* __restrict__ vals_c, float* __restrict__ poolp) {
    if ((int)blockIdx.x < downB) {
        down_nbr(idx_in, HinB, idx_out, nbr_out, cnt_out, HoutB, cap_out, zofs, blockIdx.x);
        return;
    }
    int n = *cnt_c; if (n > cap_c) n = cap_c;
    conv_bs(vprevb, wlvl, nbr_c, n, vals_c, poolp,
            blockIdx.x - downB, gridDim.x - downB, blockIdx.x & (NSHARD - 1));
}

// TAIL3: down9 + conv8 + down10 + conv9 + conv10..13 + feat + MLP at 1024
// threads (16 waves of TLP hide the serial HBM legs). Proven r6/r9 structure;
// conv7 stays in flevel i=8 (r10's absorption cost +40us — do not re-fuse).
__global__ __launch_bounds__(1024) void k_tail3(TailArgs a) {
    char* ws = a.ws;
    int* cnt = (int*)ws;
    float* poolsh = (float*)(ws + 256);
    float* wt = (float*)(ws + 32768);
    int t = threadIdx.x;

    // down9: idx8 (H=8) -> idx9 (H=4), nbr9 (into vals8), cnt9  [wave 0]
    if (t < 64)
        down_small_wave((const int*)(ws + a.idx8), 3, (int*)(ws + a.idx9),
                        (int*)(ws + a.nbr9), cnt + 9, 2, a.cap9, a.cap8 * 128);
    __syncthreads();
    // conv8: vals7 -> vals8 (n8 from previous kernel)
    {
        int n8 = cnt_load(cnt + 8); if (n8 > a.cap8) n8 = a.cap8;
        conv_small_1024((const char*)(ws + a.val7), wt + (size_t)7 * 9216,
                        (const int*)(ws + a.nbr8), n8,
                        (float*)(ws + a.val8), poolsh + 8 * 32);
    }
    __syncthreads();
    // down10: idx9 (H=4) -> idx10 (H=2), nbr10 (into vals9), cnt10  [wave 0]
    if (t < 64)
        down_small_wave((const int*)(ws + a.idx9), 2, (int*)(ws + a.idx10),
                        (int*)(ws + a.nbr10), cnt + 10, 1, a.cap10, a.cap9 * 128);
    __syncthreads();
    // conv9: vals8 -> vals9 (n9 written by down9 in THIS kernel -> cnt_load)
    {
        int n9 = cnt_load(cnt + 9); if (n9 > a.cap9) n9 = a.cap9;
        conv_small_1024((const char*)(ws + a.val8), wt + (size_t)8 * 9216,
                        (const int*)(ws + a.nbr9), n9,
                        (float*)(ws + a.val9), poolsh + 9 * 32);
    }
    __syncthreads();

    // ---- conv10..13 + feat + MLP: proven 1024-thread body ----
    const char* vals9b = (const char*)(ws + a.val9);
    const int* nbr10 = (const int*)(ws + a.nbr10);
    const int* idx10 = (const int*)(ws + a.idx10);
    __shared__ __align__(16) float v10[128];
    __shared__ float v11[32], v12[32], v13[32];
    __shared__ float feat[448], h[256], part[1024];
    __shared__ int s_i10[4], s_n10;
    int ciq = t & 7, co = (t >> 3) & 31, s = t >> 8;
    int ciq16 = ciq << 4;
    if (t == 0) s_n10 = cnt_load(cnt + 10);
    if (t < 4) s_i10[t] = idx10[t];
    __syncthreads();
    int n10 = s_n10; if (n10 > 4) n10 = 4;
    {   // conv10: 4 slot-groups x 256 threads, byte-offset gather (zero-row padded)
        const float* wl = wt + (size_t)9 * 9216;
        float4 wreg[9];
        #pragma unroll
        for (int tap = 0; tap < 9; tap++)
            wreg[tap] = *(const float4*)(wl + ((tap * 32 + co) << 5) + (ciq << 2));
        bool live = s < n10;
        int sb = live ? s : 0;
        float a0 = 0.f;
        #pragma unroll
        for (int tap = 0; tap < 9; tap++)
            a0 = fma4(*(const float4*)(vals9b + nbr10[sb * 9 + tap] + ciq16), wreg[tap], a0);
        a0 += __shfl_xor(a0, 1); a0 += __shfl_xor(a0, 2); a0 += __shfl_xor(a0, 4);
        if (ciq == 0 && live) v10[s * 32 + co] = fmaxf(a0, 0.f);
    }
    __syncthreads();
    int i10[4] = {s_i10[0], s_i10[1], s_i10[2], s_i10[3]};
    int nbr11[9];
    #pragma unroll
    for (int tap = 0; tap < 9; tap++) {
        int aa = tap / 3, bb = tap - aa * 3;
        int rr = aa - 1, cc = bb - 1;
        nbr11[tap] = ((unsigned)rr < 2u && (unsigned)cc < 2u) ? i10[rr * 2 + cc] : -1;
    }
    int n11 = ((nbr11[4] & nbr11[5] & nbr11[7] & nbr11[8]) >= 0) ? 1 : 0;
    if (s == 0) {   // conv11 from LDS v10
        const float* wl = wt + (size_t)10 * 9216;
        float a0 = 0.f;
        #pragma unroll
        for (int tap = 0; tap < 9; tap++) {
            int j = nbr11[tap];
            if (j >= 0) {
                float4 wv = *(const float4*)(wl + ((tap * 32 + co) << 5) + (ciq << 2));
                a0 = fma4(*(const float4*)(&v10[(j << 5) + (ciq << 2)]), wv, a0);
            }
        }
        a0 += __shfl_xor(a0, 1); a0 += __shfl_xor(a0, 2); a0 += __shfl_xor(a0, 4);
        if (ciq == 0) v11[co] = n11 ? fmaxf(a0, 0.f) : 0.f;
    }
    __syncthreads();
    if (s == 0) {   // conv12: center tap only
        const float* wl = wt + (size_t)11 * 9216;
        float4 wv = *(const float4*)(wl + ((4 * 32 + co) << 5) + (ciq << 2));
        float a0 = n11 ? fma4(*(const float4*)(&v11[ciq << 2]), wv, 0.f) : 0.f;
        a0 += __shfl_xor(a0, 1); a0 += __shfl_xor(a0, 2); a0 += __shfl_xor(a0, 4);
        if (ciq == 0) v12[co] = n11 ? fmaxf(a0, 0.f) : 0.f;
    }
    __syncthreads();
    if (s == 0) {   // conv13
        const float* wl = wt + (size_t)12 * 9216;
        float4 wv = *(const float4*)(wl + ((4 * 32 + co) << 5) + (ciq << 2));
        float a0 = n11 ? fma4(*(const float4*)(&v12[ciq << 2]), wv, 0.f) : 0.f;
        a0 += __shfl_xor(a0, 1); a0 += __shfl_xor(a0, 2); a0 += __shfl_xor(a0, 4);
        if (ciq == 0) v13[co] = n11 ? fmaxf(a0, 0.f) : 0.f;
    }
    __syncthreads();
    // feat assembly: levels 0..9 from pool shards, 10..13 from LDS
    if (t < 320) {
        float sum = 0.f;
        #pragma unroll
        for (int sh = 0; sh < NSHARD; sh++) sum += poolsh[sh * 448 + t];
        float c = (float)cnt_load(cnt + (t >> 5)); if (c < 1.f) c = 1.f;
        feat[t] = sum / c;
    }
    if (t < 32) {
        float s10 = 0.f;
        for (int q = 0; q < n10; q++) s10 += v10[q * 32 + t];
        float c10 = (float)n10; if (c10 < 1.f) c10 = 1.f;
        feat[320 + t] = s10 / c10;
        feat[352 + t] = n11 ? v11[t] : 0.f;
        feat[384 + t] = n11 ? v12[t] : 0.f;
        feat[416 + t] = n11 ? v13[t] : 0.f;
    }
    __syncthreads();
    // MLP stage 1: 448 -> 256 (4 k-chunks of 112)
    {
        int j = t & 255, chunk = t >> 8;
        float acc = (chunk == 0) ? a.bm1[j] : 0.f;
        int k0 = chunk * 112;
        #pragma unroll 8
        for (int k = k0; k < k0 + 112; k++) acc = fmaf(feat[k], a.wm1[k * 256 + j], acc);
        part[t] = acc;
    }
    __syncthreads();
    if (t < 256)
        h[t] = fmaxf(part[t] + part[t + 256] + part[t + 512] + part[t + 768], 0.f);
    __syncthreads();
    // MLP stage 2: 256 -> 128 (8 k-chunks of 32)
    {
        int j2 = t & 127, c2 = t >> 7;
        float a2 = (c2 == 0) ? a.bm2[j2] : 0.f;
        int kk0 = c2 * 32;
        #pragma unroll 8
        for (int k = kk0; k < kk0 + 32; k++) a2 = fmaf(h[k], a.wm2[k * 128 + j2], a2);
        part[t] = a2;
    }
    __syncthreads();
    if (t < 128) {
        float sum = 0.f;
        #pragma unroll
        for (int c = 0; c < 8; c++) sum += part[t + 128 * c];
        a.out[t] = sum;
    }
}

extern "C" void kernel_launch(void* const* d_in, const int* in_sizes, int n_in,
                              void* d_out, int out_size, void* d_ws, size_t ws_size,
                              hipStream_t stream) {
    const float* x    = (const float*)d_in[0];
    const float* mask = (const float*)d_in[1];
    const float* w1   = (const float*)d_in[2];
    const float* wsrc = (const float*)d_in[3];
    const float* wm1  = (const float*)d_in[4];
    const float* bm1  = (const float*)d_in[5];
    const float* wm2  = (const float*)d_in[6];
    const float* bm2  = (const float*)d_in[7];
    float* out = (float*)d_out;
    char* ws = (char*)d_ws;

    static const int Hb[NLVL]   = {11, 10, 9, 8, 7, 6, 5, 4, 3, 2, 1, 0, 0, 0};
    static const int caps[NLVL] = {45056, 43008, 43008, 34816, 16384, 4096,
                                   1024, 256, 64, 16, 4, 1, 1, 1};

    // ws layout: cnt[16]@0, dummy@128, pool shards@256 (16*448 f32), wt@32768
    size_t pool_off = 256;
    size_t wt_off = 32768;
    size_t off = wt_off + (size_t)13 * 9 * 1024 * 4;
    off = (off + 255) & ~(size_t)255;
    size_t coord0_off = off; off += (size_t)caps[0] * 4; off = (off + 255) & ~(size_t)255;
    size_t idx_off[NLVL], nbr_off[NLVL], val_off[NLVL];
    for (int l = 0; l < NLVL; l++) {
        size_t S = (size_t)(1 << Hb[l]) * (1 << Hb[l]);
        size_t sb = S * 4; if (sb < 16) sb = 16;
        idx_off[l] = off; off += sb; off = (off + 255) & ~(size_t)255;
        if (l >= 1) { nbr_off[l] = off; off += (size_t)caps[l] * 36; off = (off + 255) & ~(size_t)255; }
        else nbr_off[l] = 0;
        val_off[l] = off; off += (size_t)(caps[l] + 1) * 128; off = (off + 255) & ~(size_t)255;
    }

    int* cnt = (int*)ws;
    float* poolsh = (float*)(ws + pool_off);
    float* dummy = (float*)(ws + 128);
    float* wt = (float*)(ws + wt_off);

    ZeroArgs za;
    for (int l = 0; l < 13; l++) za.zoff[l] = val_off[l] + (size_t)caps[l] * 128;

    hipMemsetAsync(ws, 0, 32768, stream);   // cnt + pool shards

    k_f0<<<1493, 256, 0, stream>>>(
        (const float4*)mask, (int*)(ws + idx_off[0]), (int*)(ws + coord0_off),
        cnt, caps[0], wsrc, wt, ws, za);

    k_f1<<<5144, 256, 0, stream>>>(
        (const int*)(ws + idx_off[0]), (int*)(ws + idx_off[1]), (int*)(ws + nbr_off[1]),
        cnt + 1, caps[1], caps[0] * 128,
        x, w1, (const int*)(ws + coord0_off), cnt, caps[0],
        (float*)(ws + val_off[0]), poolsh, wm1, wm2, dummy);

    for (int i = 2; i <= 8; i++) {
        int lc = i - 1;
        int Hout = 1 << Hb[i];
        int S4 = (Hout * Hout + 3) >> 2;
        int downB = (S4 + 255) >> 8; if (downB < 1) downB = 1;
        // conv blocks capped at 768 (3 blocks/CU, full residency): each block
        // amortizes its weight preload + pipeline prologue over >=3.5 groups.
        int convB = (caps[lc] + 15) >> 4;
        if (convB > 768) convB = 768;
        k_flevel<<<downB + convB, 256, 0, stream>>>(
            downB,
            (const int*)(ws + idx_off[i - 1]), Hb[i - 1],
            (int*)(ws + idx_off[i]), (int*)(ws + nbr_off[i]), cnt + i, Hb[i], caps[i],
            caps[i - 1] * 128,
            (const char*)(ws + val_off[lc - 1]), wt + (size_t)(lc - 1) * 9216,
            (const int*)(ws + nbr_off[lc]), cnt + lc, caps[lc],
            (float*)(ws + val_off[lc]), poolsh + lc * 32);
    }

    TailArgs ta;
    ta.ws = ws;
    ta.wm1 = wm1; ta.bm1 = bm1; ta.wm2 = wm2; ta.bm2 = bm2;
    ta.out = out;
    ta.idx8 = idx_off[8];  ta.idx9 = idx_off[9];  ta.idx10 = idx_off[10];
    ta.nbr8 = nbr_off[8];  ta.nbr9 = nbr_off[9];  ta.nbr10 = nbr_off[10];
    ta.val7 = val_off[7];  ta.val8 = val_off[8];  ta.val9 = val_off[9];
    ta.cap8 = caps[8]; ta.cap9 = caps[9]; ta.cap10 = caps[10];
    k_tail3<<<1, 1024, 0, stream>>>(ta);
}

// Round 12
// 242.910 us; speedup vs baseline: 1.1760x; 1.0405x over previous
//
#include <hip/hip_runtime.h>

#define NLVL 14
#define NSHARD 16

struct ZeroArgs { unsigned long long zoff[13]; };

struct TailArgs {
    char* ws;
    const float* wm1; const float* bm1;
    const float* wm2; const float* bm2;
    float* out;
    unsigned long long idx8, idx9, idx10;
    unsigned long long nbr8, nbr9, nbr10;
    unsigned long long val7, val8, val9;
    int cap8, cap9, cap10;
};

__device__ __forceinline__ float fma4(float4 v, float4 w, float acc) {
    acc = fmaf(v.x, w.x, acc);
    acc = fmaf(v.y, w.y, acc);
    acc = fmaf(v.z, w.z, acc);
    return fmaf(v.w, w.w, acc);
}

__device__ __forceinline__ int cnt_load(const int* p) {
    // agent-scope atomic load: bypasses the CU L1 so we never see a line that
    // was cached before a same-kernel atomicAdd updated it at L2.
    return __hip_atomic_load(p, __ATOMIC_RELAXED, __HIP_MEMORY_SCOPE_AGENT);
}

// async global->LDS, 16 B per lane, wave-uniform LDS base + lane*16 dest.
#define GLDS16(gsrc, ldst) __builtin_amdgcn_global_load_lds( \
    (const __attribute__((address_space(1))) void*)(gsrc),   \
    (__attribute__((address_space(3))) void*)(ldst), 16, 0, 0)

// exclusive prefix over a 256-thread block, one atomicAdd per block.
// Entry __syncthreads makes it loop/multi-call reentrant (protects wsum reuse).
__device__ __forceinline__ int block_scan_base(int mycnt, int* gcnt, int& myoff) {
    __shared__ int wsum[4];
    __shared__ int base;
    __syncthreads();
    int lane = threadIdx.x & 63, wid = threadIdx.x >> 6;
    int scan = mycnt;
    #pragma unroll
    for (int d = 1; d < 64; d <<= 1) {
        int tv = __shfl_up(scan, d, 64);
        if (lane >= d) scan += tv;
    }
    if (lane == 63) wsum[wid] = scan;
    __syncthreads();
    if (threadIdx.x == 0) {
        int tot = 0;
        #pragma unroll
        for (int i = 0; i < 4; i++) { int tv = wsum[i]; wsum[i] = tot; tot += tv; }
        base = tot ? atomicAdd(gcnt, tot) : 0;
    }
    __syncthreads();
    myoff = wsum[wid] + scan - mycnt;
    return base;
}

// ---- level-0 mask compaction tile ----
__device__ void compact0_tile(const float4* __restrict__ mask4, int* __restrict__ idxmap,
                              int* __restrict__ coords, int* __restrict__ cnt, int cap, int tile) {
    int t = threadIdx.x;
    int g0 = tile * 1024 + t;
    float4 m[4];
    #pragma unroll
    for (int j = 0; j < 4; j++) m[j] = mask4[g0 + j * 256];
    int pr[16];
    int mycnt = 0;
    #pragma unroll
    for (int j = 0; j < 4; j++) {
        pr[4 * j + 0] = m[j].x > 0.5f;
        pr[4 * j + 1] = m[j].y > 0.5f;
        pr[4 * j + 2] = m[j].z > 0.5f;
        pr[4 * j + 3] = m[j].w > 0.5f;
        mycnt += pr[4 * j] + pr[4 * j + 1] + pr[4 * j + 2] + pr[4 * j + 3];
    }
    int myoff;
    int base = block_scan_base(mycnt, cnt, myoff);
    int slot = base + myoff;
    #pragma unroll
    for (int j = 0; j < 4; j++) {
        int e0 = (g0 + j * 256) << 2;
        int wv[4];
        #pragma unroll
        for (int k = 0; k < 4; k++) {
            wv[k] = -1;
            if (pr[4 * j + k]) {
                int sl = slot++;
                if (sl < cap) { wv[k] = sl; coords[sl] = e0 + k; }
            }
        }
        *(int4*)(idxmap + e0) = make_int4(wv[0], wv[1], wv[2], wv[3]);
    }
}

// ---- downsample + neighbor lists (byte offsets into vals_{l-1}, zero-row remap) ----
__device__ void down_nbr(const int* __restrict__ idx_in, int HinB,
                         int* __restrict__ idx_out, int* __restrict__ nbr_out,
                         int* __restrict__ cnt_out, int HoutB, int cap_out,
                         int zofs, int bb) {
    int Hout = 1 << HoutB, Hin = 1 << HinB;
    int S = Hout * Hout;
    int S4 = (S + 3) >> 2;
    int o4 = bb * 256 + threadIdx.x;
    int e0 = o4 << 2;
    int jv[4][9];
    int pr[4] = {0, 0, 0, 0};
    #pragma unroll
    for (int k = 0; k < 4; k++)
        #pragma unroll
        for (int tap = 0; tap < 9; tap++) jv[k][tap] = -1;
    if (o4 < S4) {
        if (HoutB >= 2) {
            int r = e0 >> HoutB, c0 = e0 & (Hout - 1);
            int w[3][12];
            #pragma unroll
            for (int a = 0; a < 3; a++) {
                int rr = 2 * r + a - 1;
                bool rok = (unsigned)rr < (unsigned)Hin;
                const int* rowp = idx_in + ((size_t)(rok ? rr : 0) << HinB) + 2 * c0;
                int4 L = (rok && c0 > 0) ? *(const int4*)(rowp - 4) : make_int4(-1, -1, -1, -1);
                int4 M = rok ? *(const int4*)rowp : make_int4(-1, -1, -1, -1);
                int4 R = rok ? *(const int4*)(rowp + 4) : make_int4(-1, -1, -1, -1);
                w[a][0] = L.x; w[a][1] = L.y; w[a][2]  = L.z; w[a][3]  = L.w;
                w[a][4] = M.x; w[a][5] = M.y; w[a][6]  = M.z; w[a][7]  = M.w;
                w[a][8] = R.x; w[a][9] = R.y; w[a][10] = R.z; w[a][11] = R.w;
            }
            #pragma unroll
            for (int k = 0; k < 4; k++) {
                #pragma unroll
                for (int a = 0; a < 3; a++)
                    #pragma unroll
                    for (int b = 0; b < 3; b++)
                        jv[k][a * 3 + b] = w[a][2 * k + b + 3];
                pr[k] = ((jv[k][4] & jv[k][5] & jv[k][7] & jv[k][8]) >= 0);
            }
        } else {   // Hout 1 or 2 (scalar path)
            #pragma unroll
            for (int k = 0; k < 4; k++) {
                int p = e0 + k;
                if (p < S) {
                    int r = p >> HoutB, c = p & (Hout - 1);
                    #pragma unroll
                    for (int a = 0; a < 3; a++)
                        #pragma unroll
                        for (int b = 0; b < 3; b++) {
                            int rr = 2 * r + a - 1, cc = 2 * c + b - 1;
                            if ((unsigned)rr < (unsigned)Hin && (unsigned)cc < (unsigned)Hin)
                                jv[k][a * 3 + b] = idx_in[((size_t)rr << HinB) + cc];
                        }
                    pr[k] = ((jv[k][4] & jv[k][5] & jv[k][7] & jv[k][8]) >= 0);
                }
            }
        }
    }
    int mycnt = pr[0] + pr[1] + pr[2] + pr[3];
    int myoff;
    int base = block_scan_base(mycnt, cnt_out, myoff);
    int slot = base + myoff;
    int wv[4] = {-1, -1, -1, -1};
    #pragma unroll
    for (int k = 0; k < 4; k++) {
        if (pr[k]) {
            int sl = slot++;
            if (sl < cap_out) {
                wv[k] = sl;
                #pragma unroll
                for (int tap = 0; tap < 9; tap++) {
                    int j = jv[k][tap];
                    nbr_out[sl * 9 + tap] = (j < 0) ? zofs : (j << 7);
                }
            }
        }
    }
    if (o4 < S4) {
        if (S >= 4) *(int4*)(idx_out + e0) = make_int4(wv[0], wv[1], wv[2], wv[3]);
        else {
            #pragma unroll
            for (int k = 0; k < 4; k++) if (e0 + k < S) idx_out[e0 + k] = wv[k];
        }
    }
}

// ---- single-wave downsample for S<=64 (tail levels): shfl scan, no LDS ----
// Executed by threads t<64 only (caller wraps + syncs). Sole writer of cnt_out.
__device__ void down_small_wave(const int* __restrict__ idx_in, int HinB,
                                int* __restrict__ idx_out, int* __restrict__ nbr_out,
                                int* __restrict__ cnt_out, int HoutB, int cap_out,
                                int zofs) {
    int t = threadIdx.x;   // < 64
    int Hout = 1 << HoutB, Hin = 1 << HinB, S = Hout * Hout;
    int p = t;
    int jv[9];
    int pr = 0;
    #pragma unroll
    for (int tap = 0; tap < 9; tap++) jv[tap] = -1;
    if (p < S) {
        int r = p >> HoutB, c = p & (Hout - 1);
        #pragma unroll
        for (int a = 0; a < 3; a++)
            #pragma unroll
            for (int b = 0; b < 3; b++) {
                int rr = 2 * r + a - 1, cc = 2 * c + b - 1;
                if ((unsigned)rr < (unsigned)Hin && (unsigned)cc < (unsigned)Hin)
                    jv[a * 3 + b] = idx_in[(rr << HinB) + cc];
            }
        pr = ((jv[4] & jv[5] & jv[7] & jv[8]) >= 0);
    }
    int scan = pr;
    #pragma unroll
    for (int d = 1; d < 64; d <<= 1) {
        int tv = __shfl_up(scan, d, 64);
        if (t >= d) scan += tv;
    }
    int myoff = scan - pr;
    int tot = __shfl(scan, 63, 64);
    if (p < S) {
        int wv = -1;
        if (pr && myoff < cap_out) {
            wv = myoff;
            #pragma unroll
            for (int tap = 0; tap < 9; tap++) {
                int j = jv[tap];
                nbr_out[myoff * 9 + tap] = (j < 0) ? zofs : (j << 7);
            }
        }
        idx_out[p] = wv;
    }
    if (t == 0 && tot) atomicAdd(cnt_out, tot);
}

// ---- small conv for tail (n<=64 slots), 1024 threads ----
// ALL slots staged in ONE gather round (<=576 rows x 128 B = 72 KB LDS), then
// one co per thread (wreg[9]=36 VGPR: safe under the 128-VGPR cap that
// 1024-thread blocks impose). r10 lesson: never extend to n>64 via serial
// chunking in a single-block kernel (+40us).
__device__ void conv_small_1024(const char* __restrict__ vprevb,
                                const float* __restrict__ wlvl,
                                const int* __restrict__ nbr, int n,
                                float* __restrict__ vals, float* __restrict__ poolp) {
    __shared__ __align__(16) float s_in[576 * 32];
    int t = threadIdx.x;
    int ciq = t & 7, co = (t >> 3) & 31, sp = t >> 8;   // sp in [0,4)
    float4 wreg[9];
    #pragma unroll
    for (int tap = 0; tap < 9; tap++)
        wreg[tap] = *(const float4*)(wlvl + ((tap * 32 + co) << 5) + (ciq << 2));
    int items = n * 72;   // n*9 rows x 8 16-B chunks
    for (int i = t; i < items; i += 1024) {
        int row = i >> 3, q = i & 7;
        int jb = nbr[row];   // 8 lanes broadcast same row offset
        *(float4*)&s_in[(row << 5) + (q << 2)] =
            *(const float4*)(vprevb + jb + (q << 4));
    }
    __syncthreads();
    float ps = 0.f;
    #pragma unroll 1
    for (int gp = 0; gp < 16; gp++) {
        int g = gp * 4 + sp;
        if (g >= n) break;   // uniform within each 8-lane shuffle group
        float a0 = 0.f;
        #pragma unroll
        for (int tap = 0; tap < 9; tap++) {
            float4 v = *(const float4*)&s_in[((g * 9 + tap) << 5) + (ciq << 2)];
            a0 = fma4(v, wreg[tap], a0);
        }
        a0 += __shfl_xor(a0, 1); a0 += __shfl_xor(a0, 2); a0 += __shfl_xor(a0, 4);
        if (ciq == 0) {
            float r0 = fmaxf(a0, 0.f);
            vals[((size_t)g << 5) + co] = r0;
            ps += r0;
        }
    }
    if (ciq == 0 && ps != 0.f) atomicAdd(&poolp[co], ps);
}

// ---- conv 3x3 s2 32->32: PIPELINED LDS staging, co-PAIR compute ----
// thread = (ciq = t&7, coh = (t>>3)&15 -> co {coh, coh+16}, sp = t>>7)
// r9 variant (MEASURED BEST, 245.3us): double-buffered s_in (2x18 KB) + s_j
// (2x576 B); group g+1's gather issued via global_load_lds (width 16, no
// VGPR round-trip) BEFORE group g's compute; j prefetched one group further
// in a register. (r11's register-j single-barrier variant measured 252.7 —
// the coalesced 144-thread s_j burst overlaps compute better than 5 extra
// broadcast loads serialized against the GLDS issue.)
__device__ void conv_bs(const char* __restrict__ vprevb, const float* __restrict__ wlvl,
                        const int* __restrict__ nbr, int n,
                        float* __restrict__ vals, float* __restrict__ poolp,
                        int b0, int nbk, int shard) {
    __shared__ int s_j[2][144];
    __shared__ __align__(16) float s_in[2][144 * 32];   // 2 x 18 KB
    int t = threadIdx.x;
    int ciq = t & 7, coh = (t >> 3) & 15, sp = t >> 7;
    int wid = t >> 6, lane = t & 63;
    float4 wreg[9][2];
    #pragma unroll
    for (int tap = 0; tap < 9; tap++) {
        wreg[tap][0] = *(const float4*)(wlvl + ((tap * 32 + coh) << 5) + (ciq << 2));
        wreg[tap][1] = *(const float4*)(wlvl + ((tap * 32 + coh + 16) << 5) + (ciq << 2));
    }
    float ps0 = 0.f, ps1 = 0.f;
    int ngr = (n + 15) >> 4;
    int n9 = n * 9;

    // prologue: j for first group -> s_j[0]; issue its gather; prefetch next j.
    int jreg = 0;
    if (t < 144) {
        int gi = b0 * 144 + t;
        jreg = (b0 < ngr && gi < n9) ? nbr[gi] : 0;
        s_j[0][t] = jreg;
    }
    __syncthreads();
    if (b0 < ngr) {
        const int* sj = s_j[0];
        #pragma unroll
        for (int inst = 0; inst < 5; inst++) {   // wid-strided: insts wid, wid+4, ...
            int ii = wid + inst * 4;
            if (ii < 18) {
                int chunk = (ii << 6) + lane;
                int row = chunk >> 3, q = chunk & 7;
                GLDS16(vprevb + sj[row] + (q << 4), &s_in[0][ii << 8]);
            }
        }
    }
    if (t < 144) {
        int g1 = b0 + nbk;
        int gi = g1 * 144 + t;
        jreg = (g1 < ngr && gi < n9) ? nbr[gi] : 0;
    }

    int cur = 0;
    for (int grp = b0; grp < ngr; grp += nbk) {
        __syncthreads();   // A: s_in[cur] staged (vmcnt drained by barrier)
        bool hasnext = (grp + nbk) < ngr;
        if (t < 144) s_j[cur ^ 1][t] = jreg;
        __syncthreads();   // B: s_j[cur^1] visible; s_in[cur^1] free since last iter's compute
        if (hasnext) {
            const int* sj = s_j[cur ^ 1];
            float* dst = s_in[cur ^ 1];
            #pragma unroll
            for (int inst = 0; inst < 5; inst++) {
                int ii = wid + inst * 4;
                if (ii < 18) {
                    int chunk = (ii << 6) + lane;
                    int row = chunk >> 3, q = chunk & 7;
                    GLDS16(vprevb + sj[row] + (q << 4), &dst[ii << 8]);
                }
            }
        }
        if (t < 144) {
            int g2 = grp + 2 * nbk;
            int gi = g2 * 144 + t;
            jreg = (g2 < ngr && gi < n9) ? nbr[gi] : 0;
        }
        // compute from s_in[cur] (overlaps the in-flight gather for g+1)
        const float* sb = s_in[cur];
        #pragma unroll
        for (int gp = 0; gp < 8; gp++) {
            int g = gp * 2 + sp;
            int s = (grp << 4) + g;
            float4 v[9];
            #pragma unroll
            for (int tap = 0; tap < 9; tap++)
                v[tap] = *(const float4*)&sb[((g * 9 + tap) << 5) + (ciq << 2)];
            float a0 = 0.f, a1 = 0.f;
            #pragma unroll
            for (int tap = 0; tap < 9; tap++) {
                a0 = fma4(v[tap], wreg[tap][0], a0);
                a1 = fma4(v[tap], wreg[tap][1], a1);
            }
            a0 += __shfl_xor(a0, 1); a0 += __shfl_xor(a0, 2); a0 += __shfl_xor(a0, 4);
            a1 += __shfl_xor(a1, 1); a1 += __shfl_xor(a1, 2); a1 += __shfl_xor(a1, 4);
            if (ciq == 0 && s < n) {
                float r0 = fmaxf(a0, 0.f), r1 = fmaxf(a1, 0.f);
                vals[((size_t)s << 5) + coh] = r0;
                vals[((size_t)s << 5) + coh + 16] = r1;
                ps0 += r0; ps1 += r1;
            }
        }
        cur ^= 1;
    }
    if (ciq == 0 && (ps0 != 0.f || ps1 != 0.f)) {
        atomicAdd(&poolp[shard * 448 + coh], ps0);
        atomicAdd(&poolp[shard * 448 + coh + 16], ps1);
    }
}

// ---- conv0 (5x5, cin=1): LDS-staged windows, folded pool ----
__device__ void conv0_bs(const float* __restrict__ x, const float* __restrict__ w1,
                         const int* __restrict__ coords0, int n,
                         float* __restrict__ vals0, float* __restrict__ poolp,
                         int b0, int nbk, int shard) {
    __shared__ float lw[800];
    __shared__ float lx[8][28];
    __shared__ float red[256];
    int t = threadIdx.x;
    for (int i = t; i < 800; i += 256) lw[i] = w1[i];
    int sl = t >> 5, ch = t & 31;
    float psum = 0.f;
    int ngr = (n + 7) >> 3;
    for (int grp = b0; grp < ngr; grp += nbk) {
        __syncthreads();
        if (t < 200) {
            int slot = t / 25, tap = t - slot * 25;
            int s = (grp << 3) + slot;
            float v = 0.f;
            if (s < n) {
                int p = coords0[s];
                int r = p >> 11, c = p & 2047;
                int a = tap / 5, b = tap - a * 5;
                int rr = r + a - 2, cc = c + b - 2;
                if ((unsigned)rr < 2048u && (unsigned)cc < 2048u)
                    v = x[(rr << 11) + cc];
            }
            lx[slot][tap] = v;
        }
        __syncthreads();
        int s = (grp << 3) + sl;
        float acc = 0.f;
        #pragma unroll
        for (int tap = 0; tap < 25; tap++)
            acc = fmaf(lx[sl][tap], lw[tap * 32 + ch], acc);
        if (s < n) {
            float r0 = fmaxf(acc, 0.f);
            vals0[((size_t)s << 5) + ch] = r0;
            psum += r0;
        }
    }
    __syncthreads();
    red[t] = psum;
    __syncthreads();
    if (t < 32) {
        float tot = 0.f;
        #pragma unroll
        for (int q = 0; q < 8; q++) tot += red[t + 32 * q];
        if (tot != 0.f) atomicAdd(&poolp[shard * 448 + t], tot);
    }
}

// F0 = compaction (0..1023) + weight transpose (1024..1491) + zero-rows (1492)
__global__ __launch_bounds__(256) void k_f0(
    const float4* __restrict__ mask4, int* __restrict__ idxmap,
    int* __restrict__ coords, int* __restrict__ cnt, int cap,
    const float* __restrict__ w, float* __restrict__ wt,
    char* __restrict__ wsbase, ZeroArgs za) {
    if (blockIdx.x == 1492) {
        for (int i = threadIdx.x; i < 13 * 32; i += 256)
            *(float*)(wsbase + za.zoff[i >> 5] + ((i & 31) << 2)) = 0.f;
        return;
    }
    if (blockIdx.x >= 1024) {
        int t = (int)(blockIdx.x - 1024) * 256 + threadIdx.x;
        if (t < 13 * 9 * 32 * 32) {
            int ci = t & 31, co = (t >> 5) & 31, tp = t >> 10;
            wt[(tp << 10) + (co << 5) + ci] = w[(tp << 10) + (ci << 5) + co];
        }
        return;
    }
    compact0_tile(mask4, idxmap, coords, cnt, cap, blockIdx.x);
}

// F1 = down1+nbr1 (0..1023) + conv0 (1024..5119) + wm warm (5120..5143)
__global__ __launch_bounds__(256) void k_f1(
    const int* __restrict__ idx0, int* __restrict__ idx1, int* __restrict__ nbr1,
    int* __restrict__ cnt1, int cap1, int zofs1,
    const float* __restrict__ x, const float* __restrict__ w1,
    const int* __restrict__ coords0, const int* __restrict__ cnt0, int cap0,
    float* __restrict__ vals0, float* __restrict__ poolp,
    const float* __restrict__ wm1, const float* __restrict__ wm2, float* __restrict__ dummy) {
    if (blockIdx.x < 1024) {
        down_nbr(idx0, 11, idx1, nbr1, cnt1, 10, cap1, zofs1, blockIdx.x);
        return;
    }
    if (blockIdx.x >= 5120) {
        int t = (int)(blockIdx.x - 5120) * 256 + threadIdx.x;
        const float4* a = (const float4*)wm1;
        const float4* b = (const float4*)wm2;
        float acc = 0.f;
        for (int i = t; i < 28672; i += 6144) { float4 v = a[i]; acc += v.x + v.y + v.z + v.w; }
        for (int i = t; i < 8192; i += 6144)  { float4 v = b[i]; acc += v.x + v.y + v.z + v.w; }
        if (acc == 1234.56789f) dummy[0] = acc;
        return;
    }
    int n = *cnt0; if (n > cap0) n = cap0;
    conv0_bs(x, w1, coords0, n, vals0, poolp, blockIdx.x - 1024, 4096, blockIdx.x & (NSHARD - 1));
}

// F_i (i=2..8): down_i (+nbr_i) fused with conv_{i-1} (+pool_{i-1})
__global__ __launch_bounds__(256) void k_flevel(
    int downB,
    const int* __restrict__ idx_in, int HinB,
    int* __restrict__ idx_out, int* __restrict__ nbr_out, int* __restrict__ cnt_out,
    int HoutB, int cap_out, int zofs,
    const char* __restrict__ vprevb, const float* __restrict__ wlvl,
    const int* __restrict__ nbr_c, const int* __restrict__ cnt_c, int cap_c,
    float* __restrict__ vals_c, float* __restrict__ poolp) {
    if ((int)blockIdx.x < downB) {
        down_nbr(idx_in, HinB, idx_out, nbr_out, cnt_out, HoutB, cap_out, zofs, blockIdx.x);
        return;
    }
    int n = *cnt_c; if (n > cap_c) n = cap_c;
    conv_bs(vprevb, wlvl, nbr_c, n, vals_c, poolp,
            blockIdx.x - downB, gridDim.x - downB, blockIdx.x & (NSHARD - 1));
}

// TAIL3: down9 + conv8 + down10 + conv9 + conv10..13 + feat + MLP at 1024
// threads (16 waves of TLP hide the serial HBM legs). Proven r6/r9 structure;
// conv7 stays in flevel i=8 (r10's absorption cost +40us — do not re-fuse).
__global__ __launch_bounds__(1024) void k_tail3(TailArgs a) {
    char* ws = a.ws;
    int* cnt = (int*)ws;
    float* poolsh = (float*)(ws + 256);
    float* wt = (float*)(ws + 32768);
    int t = threadIdx.x;

    // down9: idx8 (H=8) -> idx9 (H=4), nbr9 (into vals8), cnt9  [wave 0]
    if (t < 64)
        down_small_wave((const int*)(ws + a.idx8), 3, (int*)(ws + a.idx9),
                        (int*)(ws + a.nbr9), cnt + 9, 2, a.cap9, a.cap8 * 128);
    __syncthreads();
    // conv8: vals7 -> vals8 (n8 from previous kernel)
    {
        int n8 = cnt_load(cnt + 8); if (n8 > a.cap8) n8 = a.cap8;
        conv_small_1024((const char*)(ws + a.val7), wt + (size_t)7 * 9216,
                        (const int*)(ws + a.nbr8), n8,
                        (float*)(ws + a.val8), poolsh + 8 * 32);
    }
    __syncthreads();
    // down10: idx9 (H=4) -> idx10 (H=2), nbr10 (into vals9), cnt10  [wave 0]
    if (t < 64)
        down_small_wave((const int*)(ws + a.idx9), 2, (int*)(ws + a.idx10),
                        (int*)(ws + a.nbr10), cnt + 10, 1, a.cap10, a.cap9 * 128);
    __syncthreads();
    // conv9: vals8 -> vals9 (n9 written by down9 in THIS kernel -> cnt_load)
    {
        int n9 = cnt_load(cnt + 9); if (n9 > a.cap9) n9 = a.cap9;
        conv_small_1024((const char*)(ws + a.val8), wt + (size_t)8 * 9216,
                        (const int*)(ws + a.nbr9), n9,
                        (float*)(ws + a.val9), poolsh + 9 * 32);
    }
    __syncthreads();

    // ---- conv10..13 + feat + MLP: proven 1024-thread body ----
    const char* vals9b = (const char*)(ws + a.val9);
    const int* nbr10 = (const int*)(ws + a.nbr10);
    const int* idx10 = (const int*)(ws + a.idx10);
    __shared__ __align__(16) float v10[128];
    __shared__ float v11[32], v12[32], v13[32];
    __shared__ float feat[448], h[256], part[1024];
    __shared__ int s_i10[4], s_n10;
    int ciq = t & 7, co = (t >> 3) & 31, s = t >> 8;
    int ciq16 = ciq << 4;
    if (t == 0) s_n10 = cnt_load(cnt + 10);
    if (t < 4) s_i10[t] = idx10[t];
    __syncthreads();
    int n10 = s_n10; if (n10 > 4) n10 = 4;
    {   // conv10: 4 slot-groups x 256 threads, byte-offset gather (zero-row padded)
        const float* wl = wt + (size_t)9 * 9216;
        float4 wreg[9];
        #pragma unroll
        for (int tap = 0; tap < 9; tap++)
            wreg[tap] = *(const float4*)(wl + ((tap * 32 + co) << 5) + (ciq << 2));
        bool live = s < n10;
        int sb = live ? s : 0;
        float a0 = 0.f;
        #pragma unroll
        for (int tap = 0; tap < 9; tap++)
            a0 = fma4(*(const float4*)(vals9b + nbr10[sb * 9 + tap] + ciq16), wreg[tap], a0);
        a0 += __shfl_xor(a0, 1); a0 += __shfl_xor(a0, 2); a0 += __shfl_xor(a0, 4);
        if (ciq == 0 && live) v10[s * 32 + co] = fmaxf(a0, 0.f);
    }
    __syncthreads();
    int i10[4] = {s_i10[0], s_i10[1], s_i10[2], s_i10[3]};
    int nbr11[9];
    #pragma unroll
    for (int tap = 0; tap < 9; tap++) {
        int aa = tap / 3, bb = tap - aa * 3;
        int rr = aa - 1, cc = bb - 1;
        nbr11[tap] = ((unsigned)rr < 2u && (unsigned)cc < 2u) ? i10[rr * 2 + cc] : -1;
    }
    int n11 = ((nbr11[4] & nbr11[5] & nbr11[7] & nbr11[8]) >= 0) ? 1 : 0;
    if (s == 0) {   // conv11 from LDS v10
        const float* wl = wt + (size_t)10 * 9216;
        float a0 = 0.f;
        #pragma unroll
        for (int tap = 0; tap < 9; tap++) {
            int j = nbr11[tap];
            if (j >= 0) {
                float4 wv = *(const float4*)(wl + ((tap * 32 + co) << 5) + (ciq << 2));
                a0 = fma4(*(const float4*)(&v10[(j << 5) + (ciq << 2)]), wv, a0);
            }
        }
        a0 += __shfl_xor(a0, 1); a0 += __shfl_xor(a0, 2); a0 += __shfl_xor(a0, 4);
        if (ciq == 0) v11[co] = n11 ? fmaxf(a0, 0.f) : 0.f;
    }
    __syncthreads();
    if (s == 0) {   // conv12: center tap only
        const float* wl = wt + (size_t)11 * 9216;
        float4 wv = *(const float4*)(wl + ((4 * 32 + co) << 5) + (ciq << 2));
        float a0 = n11 ? fma4(*(const float4*)(&v11[ciq << 2]), wv, 0.f) : 0.f;
        a0 += __shfl_xor(a0, 1); a0 += __shfl_xor(a0, 2); a0 += __shfl_xor(a0, 4);
        if (ciq == 0) v12[co] = n11 ? fmaxf(a0, 0.f) : 0.f;
    }
    __syncthreads();
    if (s == 0) {   // conv13
        const float* wl = wt + (size_t)12 * 9216;
        float4 wv = *(const float4*)(wl + ((4 * 32 + co) << 5) + (ciq << 2));
        float a0 = n11 ? fma4(*(const float4*)(&v12[ciq << 2]), wv, 0.f) : 0.f;
        a0 += __shfl_xor(a0, 1); a0 += __shfl_xor(a0, 2); a0 += __shfl_xor(a0, 4);
        if (ciq == 0) v13[co] = n11 ? fmaxf(a0, 0.f) : 0.f;
    }
    __syncthreads();
    // feat assembly: levels 0..9 from pool shards, 10..13 from LDS
    if (t < 320) {
        float sum = 0.f;
        #pragma unroll
        for (int sh = 0; sh < NSHARD; sh++) sum += poolsh[sh * 448 + t];
        float c = (float)cnt_load(cnt + (t >> 5)); if (c < 1.f) c = 1.f;
        feat[t] = sum / c;
    }
    if (t < 32) {
        float s10 = 0.f;
        for (int q = 0; q < n10; q++) s10 += v10[q * 32 + t];
        float c10 = (float)n10; if (c10 < 1.f) c10 = 1.f;
        feat[320 + t] = s10 / c10;
        feat[352 + t] = n11 ? v11[t] : 0.f;
        feat[384 + t] = n11 ? v12[t] : 0.f;
        feat[416 + t] = n11 ? v13[t] : 0.f;
    }
    __syncthreads();
    // MLP stage 1: 448 -> 256 (4 k-chunks of 112)
    {
        int j = t & 255, chunk = t >> 8;
        float acc = (chunk == 0) ? a.bm1[j] : 0.f;
        int k0 = chunk * 112;
        #pragma unroll 8
        for (int k = k0; k < k0 + 112; k++) acc = fmaf(feat[k], a.wm1[k * 256 + j], acc);
        part[t] = acc;
    }
    __syncthreads();
    if (t < 256)
        h[t] = fmaxf(part[t] + part[t + 256] + part[t + 512] + part[t + 768], 0.f);
    __syncthreads();
    // MLP stage 2: 256 -> 128 (8 k-chunks of 32)
    {
        int j2 = t & 127, c2 = t >> 7;
        float a2 = (c2 == 0) ? a.bm2[j2] : 0.f;
        int kk0 = c2 * 32;
        #pragma unroll 8
        for (int k = kk0; k < kk0 + 32; k++) a2 = fmaf(h[k], a.wm2[k * 128 + j2], a2);
        part[t] = a2;
    }
    __syncthreads();
    if (t < 128) {
        float sum = 0.f;
        #pragma unroll
        for (int c = 0; c < 8; c++) sum += part[t + 128 * c];
        a.out[t] = sum;
    }
}

extern "C" void kernel_launch(void* const* d_in, const int* in_sizes, int n_in,
                              void* d_out, int out_size, void* d_ws, size_t ws_size,
                              hipStream_t stream) {
    const float* x    = (const float*)d_in[0];
    const float* mask = (const float*)d_in[1];
    const float* w1   = (const float*)d_in[2];
    const float* wsrc = (const float*)d_in[3];
    const float* wm1  = (const float*)d_in[4];
    const float* bm1  = (const float*)d_in[5];
    const float* wm2  = (const float*)d_in[6];
    const float* bm2  = (const float*)d_in[7];
    float* out = (float*)d_out;
    char* ws = (char*)d_ws;

    static const int Hb[NLVL]   = {11, 10, 9, 8, 7, 6, 5, 4, 3, 2, 1, 0, 0, 0};
    static const int caps[NLVL] = {45056, 43008, 43008, 34816, 16384, 4096,
                                   1024, 256, 64, 16, 4, 1, 1, 1};

    // ws layout: cnt[16]@0, dummy@128, pool shards@256 (16*448 f32), wt@32768
    size_t pool_off = 256;
    size_t wt_off = 32768;
    size_t off = wt_off + (size_t)13 * 9 * 1024 * 4;
    off = (off + 255) & ~(size_t)255;
    size_t coord0_off = off; off += (size_t)caps[0] * 4; off = (off + 255) & ~(size_t)255;
    size_t idx_off[NLVL], nbr_off[NLVL], val_off[NLVL];
    for (int l = 0; l < NLVL; l++) {
        size_t S = (size_t)(1 << Hb[l]) * (1 << Hb[l]);
        size_t sb = S * 4; if (sb < 16) sb = 16;
        idx_off[l] = off; off += sb; off = (off + 255) & ~(size_t)255;
        if (l >= 1) { nbr_off[l] = off; off += (size_t)caps[l] * 36; off = (off + 255) & ~(size_t)255; }
        else nbr_off[l] = 0;
        val_off[l] = off; off += (size_t)(caps[l] + 1) * 128; off = (off + 255) & ~(size_t)255;
    }

    int* cnt = (int*)ws;
    float* poolsh = (float*)(ws + pool_off);
    float* dummy = (float*)(ws + 128);
    float* wt = (float*)(ws + wt_off);

    ZeroArgs za;
    for (int l = 0; l < 13; l++) za.zoff[l] = val_off[l] + (size_t)caps[l] * 128;

    hipMemsetAsync(ws, 0, 32768, stream);   // cnt + pool shards

    k_f0<<<1493, 256, 0, stream>>>(
        (const float4*)mask, (int*)(ws + idx_off[0]), (int*)(ws + coord0_off),
        cnt, caps[0], wsrc, wt, ws, za);

    k_f1<<<5144, 256, 0, stream>>>(
        (const int*)(ws + idx_off[0]), (int*)(ws + idx_off[1]), (int*)(ws + nbr_off[1]),
        cnt + 1, caps[1], caps[0] * 128,
        x, w1, (const int*)(ws + coord0_off), cnt, caps[0],
        (float*)(ws + val_off[0]), poolsh, wm1, wm2, dummy);

    for (int i = 2; i <= 8; i++) {
        int lc = i - 1;
        int Hout = 1 << Hb[i];
        int S4 = (Hout * Hout + 3) >> 2;
        int downB = (S4 + 255) >> 8; if (downB < 1) downB = 1;
        // conv blocks capped at 768 (3 blocks/CU, full residency): each block
        // amortizes its weight preload + pipeline prologue over >=3.5 groups.
        int convB = (caps[lc] + 15) >> 4;
        if (convB > 768) convB = 768;
        k_flevel<<<downB + convB, 256, 0, stream>>>(
            downB,
            (const int*)(ws + idx_off[i - 1]), Hb[i - 1],
            (int*)(ws + idx_off[i]), (int*)(ws + nbr_off[i]), cnt + i, Hb[i], caps[i],
            caps[i - 1] * 128,
            (const char*)(ws + val_off[lc - 1]), wt + (size_t)(lc - 1) * 9216,
            (const int*)(ws + nbr_off[lc]), cnt + lc, caps[lc],
            (float*)(ws + val_off[lc]), poolsh + lc * 32);
    }

    TailArgs ta;
    ta.ws = ws;
    ta.wm1 = wm1; ta.bm1 = bm1; ta.wm2 = wm2; ta.bm2 = bm2;
    ta.out = out;
    ta.idx8 = idx_off[8];  ta.idx9 = idx_off[9];  ta.idx10 = idx_off[10];
    ta.nbr8 = nbr_off[8];  ta.nbr9 = nbr_off[9];  ta.nbr10 = nbr_off[10];
    ta.val7 = val_off[7];  ta.val8 = val_off[8];  ta.val9 = val_off[9];
    ta.cap8 = caps[8]; ta.cap9 = caps[9]; ta.cap10 = caps[10];
    k_tail3<<<1, 1024, 0, stream>>>(ta);
}